// Round 1
// baseline (1133.219 us; speedup 1.0000x reference)
//
#include <hip/hip_runtime.h>
#include <hip/hip_bf16.h>
#include <math.h>

// Problem constants
#define BB 2
#define NN 4096
#define PP (BB*NN)      // 8192 points total
#define KK 20
#define LEAK 0.2f
#define EPSB 1e-5f

// ---------------------------------------------------------------------------
// transpose pts (B,2,N) -> (B,N,2)
__global__ void transpose_pts(const float* __restrict__ pts, float* __restrict__ pts_t) {
    int e = blockIdx.x * 256 + threadIdx.x;
    if (e >= PP) return;
    int b = e / NN, n = e % NN;
    pts_t[(size_t)e * 2 + 0] = pts[(size_t)b * 2 * NN + n];
    pts_t[(size_t)e * 2 + 1] = pts[(size_t)b * 2 * NN + NN + n];
}

// ---------------------------------------------------------------------------
// kNN: one block per point; distances in LDS; 20x tie-break-stable argmax.
// Distance arithmetic mimics XLA-CPU: dot via fmaf (i=0 product then fused i=1),
// inner = -2*dot exact, pd = ((-xx_n) - inner) - xx_m with separate roundings.
__global__ __launch_bounds__(256) void knn_kernel(const float* __restrict__ pts,
                                                  int* __restrict__ idx) {
    __shared__ float pd[NN];
    __shared__ float rv[256];
    __shared__ int   ri[256];
    int r = blockIdx.x;            // b*N + n
    int b = r / NN, n = r % NN;
    const float* X0 = pts + (size_t)b * 2 * NN;
    const float* X1 = X0 + NN;
    int tid = threadIdx.x;
    float x0n = X0[n], x1n = X1[n];
    float xxn = __fadd_rn(__fmul_rn(x0n, x0n), __fmul_rn(x1n, x1n));
    float negxxn = __fsub_rn(0.f, xxn);
    for (int m = tid; m < NN; m += 256) {
        float x0m = X0[m], x1m = X1[m];
        float xxm = __fadd_rn(__fmul_rn(x0m, x0m), __fmul_rn(x1m, x1m));
        float dot = __builtin_fmaf(x1n, x1m, __fmul_rn(x0n, x0m));
        float inner = __fmul_rn(-2.f, dot);
        float t1 = __fsub_rn(negxxn, inner);
        pd[m] = __fsub_rn(t1, xxm);
    }
    __syncthreads();
    for (int k = 0; k < KK; ++k) {
        float bv = -INFINITY; int bi = NN;
        for (int m = tid; m < NN; m += 256) {
            float vq = pd[m];
            if (vq > bv || (vq == bv && m < bi)) { bv = vq; bi = m; }
        }
        rv[tid] = bv; ri[tid] = bi;
        __syncthreads();
        for (int s = 128; s > 0; s >>= 1) {
            if (tid < s) {
                float v2 = rv[tid + s]; int i2 = ri[tid + s];
                if (v2 > rv[tid] || (v2 == rv[tid] && i2 < ri[tid])) { rv[tid] = v2; ri[tid] = i2; }
            }
            __syncthreads();
        }
        if (tid == 0) {
            int w = ri[0];
            idx[(size_t)r * KK + k] = w;
            pd[w] = -INFINITY;
        }
        __syncthreads();
    }
}

// ---------------------------------------------------------------------------
// Generic projection GEMM.
// mode 0 (UV): cols = 2*O.  col j<O:  out u[p][j]  = sum_c w[j][c]      * X[p][c]
//                           col j>=O: out v[p][j-O]= sum_c (w[.][C+c]-w[.][c]) * X[p][c]
//              (w rows have length 2C)
// mode 1 (plain): cols = O, w rows length C, out -> outU[p][j]
__global__ __launch_bounds__(256) void proj_gemm(const float* __restrict__ X, int ldx, int C,
                                                 const float* __restrict__ W, int O, int mode,
                                                 float* __restrict__ outU, float* __restrict__ outV) {
    __shared__ float Xs[16][65];
    __shared__ float Ws[16][65];
    int row0 = blockIdx.x * 64, col0 = blockIdx.y * 64;
    int tid = threadIdx.x;
    int tx = tid % 16, ty = tid / 16;
    float acc[4][4] = {};
    for (int c0 = 0; c0 < C; c0 += 16) {
        // X tile: rows ty + i*16, k = tx
        for (int i = 0; i < 4; ++i) {
            int mm = ty + i * 16;
            float val = 0.f;
            if (c0 + tx < C) val = X[(size_t)(row0 + mm) * ldx + c0 + tx];
            Xs[tx][mm] = val;
        }
        // W tile: cols ty + i*16, k = tx
        for (int i = 0; i < 4; ++i) {
            int jj = ty + i * 16;
            int j = col0 + jj;
            float val = 0.f;
            if (c0 + tx < C) {
                if (mode == 0) {
                    if (j < O) val = W[(size_t)j * (2 * C) + c0 + tx];
                    else {
                        const float* wr = W + (size_t)(j - O) * (2 * C);
                        val = wr[C + c0 + tx] - wr[c0 + tx];
                    }
                } else {
                    val = W[(size_t)j * C + c0 + tx];
                }
            }
            Ws[tx][jj] = val;
        }
        __syncthreads();
        int kmax = (C - c0 < 16) ? (C - c0) : 16;
        for (int kk = 0; kk < kmax; ++kk) {
            float a[4], bw[4];
            #pragma unroll
            for (int i = 0; i < 4; ++i) a[i] = Xs[kk][ty * 4 + i];
            #pragma unroll
            for (int j = 0; j < 4; ++j) bw[j] = Ws[kk][tx * 4 + j];
            #pragma unroll
            for (int i = 0; i < 4; ++i)
                #pragma unroll
                for (int j = 0; j < 4; ++j)
                    acc[i][j] = fmaf(a[i], bw[j], acc[i][j]);
        }
        __syncthreads();
    }
    for (int i = 0; i < 4; ++i) {
        int rr = row0 + ty * 4 + i;
        for (int j = 0; j < 4; ++j) {
            int jg = col0 + tx * 4 + j;
            float vv = acc[i][j];
            if (mode == 0) {
                if (jg < O) outU[(size_t)rr * O + jg] = vv;
                else        outV[(size_t)rr * O + (jg - O)] = vv;
            } else {
                outU[(size_t)rr * O + jg] = vv;
            }
        }
    }
}

// ---------------------------------------------------------------------------
// Per-point gather + per-channel sum/sumsq partials + per-(point,channel) max/min over K
__global__ __launch_bounds__(256) void edge_stats(const float* __restrict__ u,
                                                  const float* __restrict__ v,
                                                  const int* __restrict__ idx,
                                                  int O,
                                                  float* __restrict__ mx, float* __restrict__ mn,
                                                  float* __restrict__ partial) {
    const int PTS = 16;
    int tid = threadIdx.x;
    int lanes = 256 / O;
    int o = tid % O, ps = tid / O;
    int ppl = PTS / lanes;
    int r0 = blockIdx.x * PTS;
    float s1 = 0.f, s2 = 0.f;
    for (int pi = 0; pi < ppl; ++pi) {
        int r = r0 + ps * ppl + pi;
        int b = r / NN;
        float vv = v[(size_t)r * O + o];
        const int* ip = idx + (size_t)r * KK;
        float bestx = -INFINITY, bestn = INFINITY;
        const float* ub = u + (size_t)b * NN * O;
        #pragma unroll 4
        for (int k = 0; k < KK; ++k) {
            int m = ip[k];
            float y = ub[(size_t)m * O + o] + vv;
            s1 += y;
            s2 = fmaf(y, y, s2);
            bestx = fmaxf(bestx, y);
            bestn = fminf(bestn, y);
        }
        mx[(size_t)r * O + o] = bestx;
        mn[(size_t)r * O + o] = bestn;
    }
    partial[((size_t)blockIdx.x * 256 + tid) * 2 + 0] = s1;
    partial[((size_t)blockIdx.x * 256 + tid) * 2 + 1] = s2;
}

// reduce partials -> per-channel scale/shift
__global__ void stats_reduce(const float* __restrict__ partial, int nblk, int O, float cnt,
                             const float* __restrict__ g, const float* __restrict__ bsh,
                             float* __restrict__ st) {
    __shared__ float c1[256], c2[256];
    int t = threadIdx.x;
    float s1 = 0.f, s2 = 0.f;
    for (int bk = 0; bk < nblk; ++bk) {
        s1 += partial[((size_t)bk * 256 + t) * 2 + 0];
        s2 += partial[((size_t)bk * 256 + t) * 2 + 1];
    }
    c1[t] = s1; c2[t] = s2;
    __syncthreads();
    if (t < O) {
        for (int l = t + O; l < 256; l += O) { s1 += c1[l]; s2 += c2[l]; }
        float mu = s1 / cnt;
        float var = s2 / cnt - mu * mu;
        float x = var + EPSB;
        float rr = rsqrtf(x);
        rr = rr * (1.5f - 0.5f * x * rr * rr);   // Newton refine
        float sc = g[t] * rr;
        st[t] = sc;
        st[O + t] = bsh[t] - mu * sc;
    }
}

// select max/min by scale sign, affine + LeakyReLU, write into xcat slice
__global__ void apply_edge(const float* __restrict__ mx, const float* __restrict__ mn,
                           const float* __restrict__ st, int O, int choff,
                           float* __restrict__ xcat) {
    int e = blockIdx.x * 256 + threadIdx.x;
    if (e >= PP * O) return;
    int r = e / O, o = e % O;
    float sc = st[o], tt = st[O + o];
    float base = (sc >= 0.f) ? mx[e] : mn[e];
    float y = fmaf(sc, base, tt);
    y = (y >= 0.f) ? y : LEAK * y;
    xcat[(size_t)r * 512 + choff + o] = y;
}

// ---------------------------------------------------------------------------
// Final BN stats over y5 (PP x 512)
__global__ __launch_bounds__(256) void final_stats(const float* __restrict__ y5,
                                                   float* __restrict__ partial) {
    int blk = blockIdx.x, t = threadIdx.x;
    float s1a = 0.f, s2a = 0.f, s1b = 0.f, s2b = 0.f;
    for (int rr = 0; rr < 128; ++rr) {
        size_t row = (size_t)(blk * 128 + rr) * 512;
        float va = y5[row + t], vb = y5[row + t + 256];
        s1a += va; s2a = fmaf(va, va, s2a);
        s1b += vb; s2b = fmaf(vb, vb, s2b);
    }
    partial[((size_t)blk * 512 + t) * 2 + 0] = s1a;
    partial[((size_t)blk * 512 + t) * 2 + 1] = s2a;
    partial[((size_t)blk * 512 + t + 256) * 2 + 0] = s1b;
    partial[((size_t)blk * 512 + t + 256) * 2 + 1] = s2b;
}

__global__ void final_reduce(const float* __restrict__ partial, int nblk, float cnt,
                             const float* __restrict__ g, const float* __restrict__ bsh,
                             float* __restrict__ st) {
    int c = threadIdx.x;  // 512 threads
    float s1 = 0.f, s2 = 0.f;
    for (int bk = 0; bk < nblk; ++bk) {
        s1 += partial[((size_t)bk * 512 + c) * 2 + 0];
        s2 += partial[((size_t)bk * 512 + c) * 2 + 1];
    }
    float mu = s1 / cnt;
    float var = s2 / cnt - mu * mu;
    float x = var + EPSB;
    float rr = rsqrtf(x);
    rr = rr * (1.5f - 0.5f * x * rr * rr);
    float sc = g[c] * rr;
    st[c] = sc;
    st[512 + c] = bsh[c] - mu * sc;
}

// affine+lrelu + transpose (B,N,512) -> (B,512,N)
__global__ __launch_bounds__(256) void final_apply(const float* __restrict__ y5,
                                                   const float* __restrict__ st,
                                                   float* __restrict__ out) {
    __shared__ float tile[32][33];
    int n0 = blockIdx.x * 32, o0 = blockIdx.y * 32, b = blockIdx.z;
    int tx = threadIdx.x, ty = threadIdx.y;
    for (int i = 0; i < 4; ++i) {
        int nl = ty + i * 8;
        tile[nl][tx] = y5[((size_t)(b * NN + n0 + nl)) * 512 + o0 + tx];
    }
    __syncthreads();
    for (int i = 0; i < 4; ++i) {
        int ol = ty + i * 8;
        int o = o0 + ol;
        float sc = st[o], tt = st[512 + o];
        float yv = fmaf(sc, tile[tx][ol], tt);
        yv = (yv >= 0.f) ? yv : LEAK * yv;
        out[((size_t)b * 512 + o) * NN + n0 + tx] = yv;
    }
}

// ---------------------------------------------------------------------------
extern "C" void kernel_launch(void* const* d_in, const int* in_sizes, int n_in,
                              void* d_out, int out_size, void* d_ws, size_t ws_size,
                              hipStream_t stream) {
    const float* pts = (const float*)d_in[0];
    const float* w[5]; const float* g[5]; const float* bsh[5];
    for (int i = 0; i < 5; ++i) {
        w[i]   = (const float*)d_in[1 + 3 * i];
        g[i]   = (const float*)d_in[2 + 3 * i];
        bsh[i] = (const float*)d_in[3 + 3 * i];
    }
    float* out = (float*)d_out;

    // workspace layout
    float* xcat = (float*)d_ws;                  // PP*512
    float* u    = xcat + (size_t)PP * 512;       // PP*256
    float* v    = u    + (size_t)PP * 256;       // PP*256
    float* mxb  = v    + (size_t)PP * 256;       // PP*256
    float* mnb  = mxb  + (size_t)PP * 256;       // PP*256
    float* y5   = u;                             // overlay u+v (PP*512)
    float* ptst = mnb  + (size_t)PP * 256;       // PP*2
    int*   idxb = (int*)(ptst + (size_t)PP * 2); // PP*20
    float* part = (float*)(idxb + (size_t)PP * KK); // up to 512*256*2
    float* st   = part + (size_t)512 * 256 * 2;  // 1024

    transpose_pts<<<(PP + 255) / 256, 256, 0, stream>>>(pts, ptst);
    knn_kernel<<<PP, 256, 0, stream>>>(pts, idxb);

    struct LayerCfg { int C, O, choff, ldxoff; };
    // layer1: X = ptst (ldx=2); layers 2-4: X = xcat + ldxoff (ldx=512)
    const int Cs[4]    = {2, 64, 64, 128};
    const int Os[4]    = {64, 64, 128, 256};
    const int choffs[4]= {0, 64, 128, 256};
    const int inoffs[4]= {0, 0, 64, 128};

    for (int li = 0; li < 4; ++li) {
        const float* X  = (li == 0) ? ptst : (xcat + inoffs[li]);
        int ldx         = (li == 0) ? 2 : 512;
        int C = Cs[li], O = Os[li];
        dim3 gg(PP / 64, (2 * O) / 64);
        proj_gemm<<<gg, 256, 0, stream>>>(X, ldx, C, w[li], O, 0, u, v);
        edge_stats<<<PP / 16, 256, 0, stream>>>(u, v, idxb, O, mxb, mnb, part);
        stats_reduce<<<1, 256, 0, stream>>>(part, PP / 16, O, (float)((size_t)PP * KK),
                                            g[li], bsh[li], st);
        apply_edge<<<(PP * O + 255) / 256, 256, 0, stream>>>(mxb, mnb, st, O, choffs[li], xcat);
    }

    // final conv1d 512->512 + BN + lrelu, output transposed to (B,512,N)
    dim3 gf(PP / 64, 512 / 64);
    proj_gemm<<<gf, 256, 0, stream>>>(xcat, 512, 512, w[4], 512, 1, y5, nullptr);
    final_stats<<<64, 256, 0, stream>>>(y5, part);
    final_reduce<<<1, 512, 0, stream>>>(part, 64, (float)PP, g[4], bsh[4], st);
    final_apply<<<dim3(NN / 32, 512 / 32, BB), dim3(32, 8), 0, stream>>>(y5, st, out);
}

// Round 2
// 466.635 us; speedup vs baseline: 2.4285x; 2.4285x over previous
//
#include <hip/hip_runtime.h>
#include <hip/hip_bf16.h>
#include <math.h>

// Problem constants
#define BB 2
#define NN 4096
#define PP (BB*NN)      // 8192 points total
#define KK 20
#define LEAK 0.2f
#define EPSB 1e-5f

// ---------------------------------------------------------------------------
// transpose pts (B,2,N) -> (B,N,2)
__global__ void transpose_pts(const float* __restrict__ pts, float* __restrict__ pts_t) {
    int e = blockIdx.x * 256 + threadIdx.x;
    if (e >= PP) return;
    int b = e / NN, n = e % NN;
    pts_t[(size_t)e * 2 + 0] = pts[(size_t)b * 2 * NN + n];
    pts_t[(size_t)e * 2 + 1] = pts[(size_t)b * 2 * NN + NN + n];
}

// ---------------------------------------------------------------------------
// kNN v2: sort-then-merge.
// Each thread owns 16 candidates (m = q*256 + tid), packs (sortable-float-key
// <<32 | (NN-1-m)) into u64 (ties -> lower index wins under max), bitonic-sorts
// them in registers (static indices), writes the sorted list to LDS, then a
// 20-step tournament merge picks the global top-20.
// Distance arithmetic is bit-identical to the verified R1 version.
__global__ __launch_bounds__(256) void knn_kernel(const float* __restrict__ pts,
                                                  int* __restrict__ idx) {
    __shared__ unsigned long long lists[256][17];   // +1 pad: 4-way banks (free-ish)
    __shared__ unsigned long long wbuf[2][4];
    int r = blockIdx.x;            // b*N + n
    int b = r >> 12, n = r & (NN - 1);
    const float* X0 = pts + (size_t)b * 2 * NN;
    const float* X1 = X0 + NN;
    int tid = threadIdx.x;
    float x0n = X0[n], x1n = X1[n];
    float xxn = __fadd_rn(__fmul_rn(x0n, x0n), __fmul_rn(x1n, x1n));
    float negxxn = __fsub_rn(0.f, xxn);

    unsigned long long a[16];
    #pragma unroll
    for (int q = 0; q < 16; ++q) {
        int m = q * 256 + tid;
        float x0m = X0[m], x1m = X1[m];
        float xxm = __fadd_rn(__fmul_rn(x0m, x0m), __fmul_rn(x1m, x1m));
        float dot = __builtin_fmaf(x1n, x1m, __fmul_rn(x0n, x0m));
        float inner = __fmul_rn(-2.f, dot);
        float t1 = __fsub_rn(negxxn, inner);
        float pdv = __fsub_rn(t1, xxm);
        unsigned int ub = __float_as_uint(pdv);
        unsigned int fk = (ub & 0x80000000u) ? ~ub : (ub | 0x80000000u);
        a[q] = ((unsigned long long)fk << 32) | (unsigned int)(NN - 1 - m);
    }

    // bitonic sort ascending (all indices compile-time after unroll)
    #pragma unroll
    for (int k = 2; k <= 16; k <<= 1) {
        #pragma unroll
        for (int j = k >> 1; j > 0; j >>= 1) {
            #pragma unroll
            for (int i = 0; i < 16; ++i) {
                int l = i ^ j;
                if (l > i) {
                    bool dir = ((i & k) == 0);     // true -> ascending block
                    unsigned long long x = a[i], y = a[l];
                    bool sw = dir ? (x > y) : (x < y);
                    if (sw) { a[i] = y; a[l] = x; }
                }
            }
        }
    }
    #pragma unroll
    for (int q = 0; q < 16; ++q) lists[tid][q] = a[q];

    // tournament merge: 20 rounds of block-wide 64-bit max
    int h = 15;
    unsigned long long hk = lists[tid][15];   // own row: no barrier needed
    for (int k = 0; k < KK; ++k) {
        unsigned long long mk = hk;
        #pragma unroll
        for (int s = 32; s > 0; s >>= 1) {
            unsigned long long o = __shfl_xor(mk, s, 64);
            if (o > mk) mk = o;
        }
        if ((tid & 63) == 0) wbuf[k & 1][tid >> 6] = mk;
        __syncthreads();
        unsigned long long g0 = wbuf[k & 1][0], g1 = wbuf[k & 1][1];
        unsigned long long g2 = wbuf[k & 1][2], g3 = wbuf[k & 1][3];
        unsigned long long ga = g0 > g1 ? g0 : g1;
        unsigned long long gb = g2 > g3 ? g2 : g3;
        unsigned long long gm = ga > gb ? ga : gb;
        if (tid == 0) {
            int m = NN - 1 - (int)(gm & 0xFFFFFFFFu);
            idx[(size_t)r * KK + k] = m;
        }
        if (hk == gm) { --h; hk = (h >= 0) ? lists[tid][h] : 0ULL; }
    }
}

// ---------------------------------------------------------------------------
// Generic projection GEMM.
// mode 0 (UV): cols = 2*O.  col j<O:  out u[p][j]  = sum_c w[j][c]      * X[p][c]
//                           col j>=O: out v[p][j-O]= sum_c (w[.][C+c]-w[.][c]) * X[p][c]
//              (w rows have length 2C)
// mode 1 (plain): cols = O, w rows length C, out -> outU[p][j]
__global__ __launch_bounds__(256) void proj_gemm(const float* __restrict__ X, int ldx, int C,
                                                 const float* __restrict__ W, int O, int mode,
                                                 float* __restrict__ outU, float* __restrict__ outV) {
    __shared__ float Xs[16][65];
    __shared__ float Ws[16][65];
    int row0 = blockIdx.x * 64, col0 = blockIdx.y * 64;
    int tid = threadIdx.x;
    int tx = tid % 16, ty = tid / 16;
    float acc[4][4] = {};
    for (int c0 = 0; c0 < C; c0 += 16) {
        for (int i = 0; i < 4; ++i) {
            int mm = ty + i * 16;
            float val = 0.f;
            if (c0 + tx < C) val = X[(size_t)(row0 + mm) * ldx + c0 + tx];
            Xs[tx][mm] = val;
        }
        for (int i = 0; i < 4; ++i) {
            int jj = ty + i * 16;
            int j = col0 + jj;
            float val = 0.f;
            if (c0 + tx < C) {
                if (mode == 0) {
                    if (j < O) val = W[(size_t)j * (2 * C) + c0 + tx];
                    else {
                        const float* wr = W + (size_t)(j - O) * (2 * C);
                        val = wr[C + c0 + tx] - wr[c0 + tx];
                    }
                } else {
                    val = W[(size_t)j * C + c0 + tx];
                }
            }
            Ws[tx][jj] = val;
        }
        __syncthreads();
        int kmax = (C - c0 < 16) ? (C - c0) : 16;
        for (int kk = 0; kk < kmax; ++kk) {
            float a[4], bw[4];
            #pragma unroll
            for (int i = 0; i < 4; ++i) a[i] = Xs[kk][ty * 4 + i];
            #pragma unroll
            for (int j = 0; j < 4; ++j) bw[j] = Ws[kk][tx * 4 + j];
            #pragma unroll
            for (int i = 0; i < 4; ++i)
                #pragma unroll
                for (int j = 0; j < 4; ++j)
                    acc[i][j] = fmaf(a[i], bw[j], acc[i][j]);
        }
        __syncthreads();
    }
    for (int i = 0; i < 4; ++i) {
        int rr = row0 + ty * 4 + i;
        for (int j = 0; j < 4; ++j) {
            int jg = col0 + tx * 4 + j;
            float vv = acc[i][j];
            if (mode == 0) {
                if (jg < O) outU[(size_t)rr * O + jg] = vv;
                else        outV[(size_t)rr * O + (jg - O)] = vv;
            } else {
                outU[(size_t)rr * O + jg] = vv;
            }
        }
    }
}

// ---------------------------------------------------------------------------
// Per-point gather + per-channel sum/sumsq partials + per-(point,channel) max/min over K
__global__ __launch_bounds__(256) void edge_stats(const float* __restrict__ u,
                                                  const float* __restrict__ v,
                                                  const int* __restrict__ idx,
                                                  int O,
                                                  float* __restrict__ mx, float* __restrict__ mn,
                                                  float* __restrict__ partial) {
    const int PTS = 16;
    int tid = threadIdx.x;
    int lanes = 256 / O;
    int o = tid % O, ps = tid / O;
    int ppl = PTS / lanes;
    int r0 = blockIdx.x * PTS;
    float s1 = 0.f, s2 = 0.f;
    for (int pi = 0; pi < ppl; ++pi) {
        int r = r0 + ps * ppl + pi;
        int b = r / NN;
        float vv = v[(size_t)r * O + o];
        const int* ip = idx + (size_t)r * KK;
        float bestx = -INFINITY, bestn = INFINITY;
        const float* ub = u + (size_t)b * NN * O;
        #pragma unroll 4
        for (int k = 0; k < KK; ++k) {
            int m = ip[k];
            float y = ub[(size_t)m * O + o] + vv;
            s1 += y;
            s2 = fmaf(y, y, s2);
            bestx = fmaxf(bestx, y);
            bestn = fminf(bestn, y);
        }
        mx[(size_t)r * O + o] = bestx;
        mn[(size_t)r * O + o] = bestn;
    }
    partial[((size_t)blockIdx.x * 256 + tid) * 2 + 0] = s1;
    partial[((size_t)blockIdx.x * 256 + tid) * 2 + 1] = s2;
}

// reduce partials -> per-channel scale/shift.  grid = O blocks, 256 threads.
__global__ __launch_bounds__(256) void stats_reduce(const float* __restrict__ partial, int nblk,
                                                    int O, float cnt,
                                                    const float* __restrict__ g,
                                                    const float* __restrict__ bsh,
                                                    float* __restrict__ st) {
    __shared__ float r1[4], r2[4];
    int o = blockIdx.x, tid = threadIdx.x;
    int lanes = 256 / O;
    int total = nblk * lanes;
    float s1 = 0.f, s2 = 0.f;
    for (int t = tid; t < total; t += 256) {
        int blk = t / lanes, ps = t - blk * lanes;
        size_t base = ((size_t)blk * 256 + (size_t)ps * O + o) * 2;
        s1 += partial[base];
        s2 += partial[base + 1];
    }
    #pragma unroll
    for (int s = 32; s > 0; s >>= 1) {
        s1 += __shfl_down(s1, s, 64);
        s2 += __shfl_down(s2, s, 64);
    }
    if ((tid & 63) == 0) { r1[tid >> 6] = s1; r2[tid >> 6] = s2; }
    __syncthreads();
    if (tid == 0) {
        s1 = r1[0] + r1[1] + r1[2] + r1[3];
        s2 = r2[0] + r2[1] + r2[2] + r2[3];
        float mu = s1 / cnt;
        float var = s2 / cnt - mu * mu;
        float x = var + EPSB;
        float rr = rsqrtf(x);
        rr = rr * (1.5f - 0.5f * x * rr * rr);   // Newton refine
        float sc = g[o] * rr;
        st[o] = sc;
        st[O + o] = bsh[o] - mu * sc;
    }
}

// select max/min by scale sign, affine + LeakyReLU, write into xcat slice
__global__ void apply_edge(const float* __restrict__ mx, const float* __restrict__ mn,
                           const float* __restrict__ st, int O, int choff,
                           float* __restrict__ xcat) {
    int e = blockIdx.x * 256 + threadIdx.x;
    if (e >= PP * O) return;
    int r = e / O, o = e % O;
    float sc = st[o], tt = st[O + o];
    float base = (sc >= 0.f) ? mx[e] : mn[e];
    float y = fmaf(sc, base, tt);
    y = (y >= 0.f) ? y : LEAK * y;
    xcat[(size_t)r * 512 + choff + o] = y;
}

// ---------------------------------------------------------------------------
// Final BN stats over y5 (PP x 512)
__global__ __launch_bounds__(256) void final_stats(const float* __restrict__ y5,
                                                   float* __restrict__ partial) {
    int blk = blockIdx.x, t = threadIdx.x;
    float s1a = 0.f, s2a = 0.f, s1b = 0.f, s2b = 0.f;
    for (int rr = 0; rr < 128; ++rr) {
        size_t row = (size_t)(blk * 128 + rr) * 512;
        float va = y5[row + t], vb = y5[row + t + 256];
        s1a += va; s2a = fmaf(va, va, s2a);
        s1b += vb; s2b = fmaf(vb, vb, s2b);
    }
    partial[((size_t)blk * 512 + t) * 2 + 0] = s1a;
    partial[((size_t)blk * 512 + t) * 2 + 1] = s2a;
    partial[((size_t)blk * 512 + t + 256) * 2 + 0] = s1b;
    partial[((size_t)blk * 512 + t + 256) * 2 + 1] = s2b;
}

// grid = 512 blocks, 64 threads: one channel per block
__global__ __launch_bounds__(64) void final_reduce(const float* __restrict__ partial, int nblk,
                                                   float cnt,
                                                   const float* __restrict__ g,
                                                   const float* __restrict__ bsh,
                                                   float* __restrict__ st) {
    int c = blockIdx.x, tid = threadIdx.x;
    float s1 = 0.f, s2 = 0.f;
    for (int bk = tid; bk < nblk; bk += 64) {
        size_t base = ((size_t)bk * 512 + c) * 2;
        s1 += partial[base];
        s2 += partial[base + 1];
    }
    #pragma unroll
    for (int s = 32; s > 0; s >>= 1) {
        s1 += __shfl_down(s1, s, 64);
        s2 += __shfl_down(s2, s, 64);
    }
    if (tid == 0) {
        float mu = s1 / cnt;
        float var = s2 / cnt - mu * mu;
        float x = var + EPSB;
        float rr = rsqrtf(x);
        rr = rr * (1.5f - 0.5f * x * rr * rr);
        float sc = g[c] * rr;
        st[c] = sc;
        st[512 + c] = bsh[c] - mu * sc;
    }
}

// affine+lrelu + transpose (B,N,512) -> (B,512,N)
__global__ __launch_bounds__(256) void final_apply(const float* __restrict__ y5,
                                                   const float* __restrict__ st,
                                                   float* __restrict__ out) {
    __shared__ float tile[32][33];
    int n0 = blockIdx.x * 32, o0 = blockIdx.y * 32, b = blockIdx.z;
    int tx = threadIdx.x, ty = threadIdx.y;
    for (int i = 0; i < 4; ++i) {
        int nl = ty + i * 8;
        tile[nl][tx] = y5[((size_t)(b * NN + n0 + nl)) * 512 + o0 + tx];
    }
    __syncthreads();
    for (int i = 0; i < 4; ++i) {
        int ol = ty + i * 8;
        int o = o0 + ol;
        float sc = st[o], tt = st[512 + o];
        float yv = fmaf(sc, tile[tx][ol], tt);
        yv = (yv >= 0.f) ? yv : LEAK * yv;
        out[((size_t)b * 512 + o) * NN + n0 + tx] = yv;
    }
}

// ---------------------------------------------------------------------------
extern "C" void kernel_launch(void* const* d_in, const int* in_sizes, int n_in,
                              void* d_out, int out_size, void* d_ws, size_t ws_size,
                              hipStream_t stream) {
    const float* pts = (const float*)d_in[0];
    const float* w[5]; const float* g[5]; const float* bsh[5];
    for (int i = 0; i < 5; ++i) {
        w[i]   = (const float*)d_in[1 + 3 * i];
        g[i]   = (const float*)d_in[2 + 3 * i];
        bsh[i] = (const float*)d_in[3 + 3 * i];
    }
    float* out = (float*)d_out;

    // workspace layout
    float* xcat = (float*)d_ws;                  // PP*512
    float* u    = xcat + (size_t)PP * 512;       // PP*256
    float* v    = u    + (size_t)PP * 256;       // PP*256
    float* mxb  = v    + (size_t)PP * 256;       // PP*256
    float* mnb  = mxb  + (size_t)PP * 256;       // PP*256
    float* y5   = u;                             // overlay u+v (PP*512)
    float* ptst = mnb  + (size_t)PP * 256;       // PP*2
    int*   idxb = (int*)(ptst + (size_t)PP * 2); // PP*20
    float* part = (float*)(idxb + (size_t)PP * KK); // up to 512*256*2
    float* st   = part + (size_t)512 * 256 * 2;  // 1024

    transpose_pts<<<(PP + 255) / 256, 256, 0, stream>>>(pts, ptst);
    knn_kernel<<<PP, 256, 0, stream>>>(pts, idxb);

    const int Cs[4]    = {2, 64, 64, 128};
    const int Os[4]    = {64, 64, 128, 256};
    const int choffs[4]= {0, 64, 128, 256};
    const int inoffs[4]= {0, 0, 64, 128};

    for (int li = 0; li < 4; ++li) {
        const float* X  = (li == 0) ? ptst : (xcat + inoffs[li]);
        int ldx         = (li == 0) ? 2 : 512;
        int C = Cs[li], O = Os[li];
        dim3 gg(PP / 64, (2 * O) / 64);
        proj_gemm<<<gg, 256, 0, stream>>>(X, ldx, C, w[li], O, 0, u, v);
        edge_stats<<<PP / 16, 256, 0, stream>>>(u, v, idxb, O, mxb, mnb, part);
        stats_reduce<<<O, 256, 0, stream>>>(part, PP / 16, O, (float)((size_t)PP * KK),
                                            g[li], bsh[li], st);
        apply_edge<<<(PP * O + 255) / 256, 256, 0, stream>>>(mxb, mnb, st, O, choffs[li], xcat);
    }

    // final conv1d 512->512 + BN + lrelu, output transposed to (B,512,N)
    dim3 gf(PP / 64, 512 / 64);
    proj_gemm<<<gf, 256, 0, stream>>>(xcat, 512, 512, w[4], 512, 1, y5, nullptr);
    final_stats<<<64, 256, 0, stream>>>(y5, part);
    final_reduce<<<512, 64, 0, stream>>>(part, 64, (float)PP, g[4], bsh[4], st);
    final_apply<<<dim3(NN / 32, 512 / 32, BB), dim3(32, 8), 0, stream>>>(y5, st, out);
}

// Round 3
// 452.707 us; speedup vs baseline: 2.5032x; 1.0308x over previous
//
#include <hip/hip_runtime.h>
#include <hip/hip_bf16.h>
#include <math.h>

// Problem constants
#define BB 2
#define NN 4096
#define PP (BB*NN)      // 8192 points total
#define KK 20
#define LEAK 0.2f
#define EPSB 1e-5f

// ---------------------------------------------------------------------------
// transpose pts (B,2,N) -> (B,N,2)
__global__ void transpose_pts(const float* __restrict__ pts, float* __restrict__ pts_t) {
    int e = blockIdx.x * 256 + threadIdx.x;
    if (e >= PP) return;
    int b = e / NN, n = e % NN;
    pts_t[(size_t)e * 2 + 0] = pts[(size_t)b * 2 * NN + n];
    pts_t[(size_t)e * 2 + 1] = pts[(size_t)b * 2 * NN + NN + n];
}

// ---------------------------------------------------------------------------
// kNN v3: register-resident sort-then-merge (no LDS lists).
// Each thread owns 16 candidates, packs (sortable-float-key <<32 | (NN-1-m))
// into u64, bitonic-sorts in registers, then 20 tournament rounds. The winner
// thread re-derives its next head via an unrolled compile-time select chain
// (no dynamic indexing -> no scratch, no LDS). LDS use: 64 B.
__global__ __launch_bounds__(256) void knn_kernel(const float* __restrict__ pts,
                                                  int* __restrict__ idx) {
    __shared__ unsigned long long wbuf[2][4];
    int r = blockIdx.x;            // b*N + n
    int b = r >> 12, n = r & (NN - 1);
    const float* X0 = pts + (size_t)b * 2 * NN;
    const float* X1 = X0 + NN;
    int tid = threadIdx.x;
    float x0n = X0[n], x1n = X1[n];
    float xxn = __fadd_rn(__fmul_rn(x0n, x0n), __fmul_rn(x1n, x1n));
    float negxxn = __fsub_rn(0.f, xxn);

    unsigned long long a[16];
    #pragma unroll
    for (int q = 0; q < 16; ++q) {
        int m = q * 256 + tid;
        float x0m = X0[m], x1m = X1[m];
        float xxm = __fadd_rn(__fmul_rn(x0m, x0m), __fmul_rn(x1m, x1m));
        float dot = __builtin_fmaf(x1n, x1m, __fmul_rn(x0n, x0m));
        float inner = __fmul_rn(-2.f, dot);
        float t1 = __fsub_rn(negxxn, inner);
        float pdv = __fsub_rn(t1, xxm);
        unsigned int ub = __float_as_uint(pdv);
        unsigned int fk = (ub & 0x80000000u) ? ~ub : (ub | 0x80000000u);
        a[q] = ((unsigned long long)fk << 32) | (unsigned int)(NN - 1 - m);
    }

    // bitonic sort ascending (a[15] = max); all indices compile-time
    #pragma unroll
    for (int k = 2; k <= 16; k <<= 1) {
        #pragma unroll
        for (int j = k >> 1; j > 0; j >>= 1) {
            #pragma unroll
            for (int i = 0; i < 16; ++i) {
                int l = i ^ j;
                if (l > i) {
                    bool dir = ((i & k) == 0);
                    unsigned long long x = a[i], y = a[l];
                    bool sw = dir ? (x > y) : (x < y);
                    if (sw) { a[i] = y; a[l] = x; }
                }
            }
        }
    }

    int h = 15;
    unsigned long long hk = a[15];
    for (int k = 0; k < KK; ++k) {
        unsigned long long mk = hk;
        #pragma unroll
        for (int s = 32; s > 0; s >>= 1) {
            unsigned long long o = __shfl_xor(mk, s, 64);
            if (o > mk) mk = o;
        }
        if ((tid & 63) == 0) wbuf[k & 1][tid >> 6] = mk;
        __syncthreads();
        unsigned long long g0 = wbuf[k & 1][0], g1 = wbuf[k & 1][1];
        unsigned long long g2 = wbuf[k & 1][2], g3 = wbuf[k & 1][3];
        unsigned long long ga = g0 > g1 ? g0 : g1;
        unsigned long long gb = g2 > g3 ? g2 : g3;
        unsigned long long gm = ga > gb ? ga : gb;
        if (tid == 0) {
            int m = NN - 1 - (int)(gm & 0xFFFFFFFFu);
            idx[(size_t)r * KK + k] = m;
        }
        if (hk == gm) {            // unique winner (index embedded in key)
            --h;
            unsigned long long nk = 0ULL;
            #pragma unroll
            for (int t = 0; t < 15; ++t) nk = (h == t) ? a[t] : nk;
            hk = nk;
        }
    }
}

// ---------------------------------------------------------------------------
// Generic projection GEMM.
// mode 0 (UV): cols = 2*O.  col j<O:  out u[p][j]  = sum_c w[j][c]      * X[p][c]
//                           col j>=O: out v[p][j-O]= sum_c (w[.][C+c]-w[.][c]) * X[p][c]
// mode 1 (plain): cols = O, w rows length C, out -> outU[p][j]
__global__ __launch_bounds__(256) void proj_gemm(const float* __restrict__ X, int ldx, int C,
                                                 const float* __restrict__ W, int O, int mode,
                                                 float* __restrict__ outU, float* __restrict__ outV) {
    __shared__ float Xs[16][65];
    __shared__ float Ws[16][65];
    int row0 = blockIdx.x * 64, col0 = blockIdx.y * 64;
    int tid = threadIdx.x;
    int tx = tid % 16, ty = tid / 16;
    float acc[4][4] = {};
    for (int c0 = 0; c0 < C; c0 += 16) {
        for (int i = 0; i < 4; ++i) {
            int mm = ty + i * 16;
            float val = 0.f;
            if (c0 + tx < C) val = X[(size_t)(row0 + mm) * ldx + c0 + tx];
            Xs[tx][mm] = val;
        }
        for (int i = 0; i < 4; ++i) {
            int jj = ty + i * 16;
            int j = col0 + jj;
            float val = 0.f;
            if (c0 + tx < C) {
                if (mode == 0) {
                    if (j < O) val = W[(size_t)j * (2 * C) + c0 + tx];
                    else {
                        const float* wr = W + (size_t)(j - O) * (2 * C);
                        val = wr[C + c0 + tx] - wr[c0 + tx];
                    }
                } else {
                    val = W[(size_t)j * C + c0 + tx];
                }
            }
            Ws[tx][jj] = val;
        }
        __syncthreads();
        int kmax = (C - c0 < 16) ? (C - c0) : 16;
        for (int kk = 0; kk < kmax; ++kk) {
            float a[4], bw[4];
            #pragma unroll
            for (int i = 0; i < 4; ++i) a[i] = Xs[kk][ty * 4 + i];
            #pragma unroll
            for (int j = 0; j < 4; ++j) bw[j] = Ws[kk][tx * 4 + j];
            #pragma unroll
            for (int i = 0; i < 4; ++i)
                #pragma unroll
                for (int j = 0; j < 4; ++j)
                    acc[i][j] = fmaf(a[i], bw[j], acc[i][j]);
        }
        __syncthreads();
    }
    for (int i = 0; i < 4; ++i) {
        int rr = row0 + ty * 4 + i;
        for (int j = 0; j < 4; ++j) {
            int jg = col0 + tx * 4 + j;
            float vv = acc[i][j];
            if (mode == 0) {
                if (jg < O) outU[(size_t)rr * O + jg] = vv;
                else        outV[(size_t)rr * O + (jg - O)] = vv;
            } else {
                outU[(size_t)rr * O + jg] = vv;
            }
        }
    }
}

// ---------------------------------------------------------------------------
// Per-point gather + per-channel sum/sumsq partials + per-(point,channel) max/min over K
__global__ __launch_bounds__(256) void edge_stats(const float* __restrict__ u,
                                                  const float* __restrict__ v,
                                                  const int* __restrict__ idx,
                                                  int O,
                                                  float* __restrict__ mx, float* __restrict__ mn,
                                                  float* __restrict__ partial) {
    const int PTS = 16;
    int tid = threadIdx.x;
    int lanes = 256 / O;
    int o = tid % O, ps = tid / O;
    int ppl = PTS / lanes;
    int r0 = blockIdx.x * PTS;
    float s1 = 0.f, s2 = 0.f;
    for (int pi = 0; pi < ppl; ++pi) {
        int r = r0 + ps * ppl + pi;
        int b = r / NN;
        float vv = v[(size_t)r * O + o];
        const int* ip = idx + (size_t)r * KK;
        float bestx = -INFINITY, bestn = INFINITY;
        const float* ub = u + (size_t)b * NN * O;
        #pragma unroll 4
        for (int k = 0; k < KK; ++k) {
            int m = ip[k];
            float y = ub[(size_t)m * O + o] + vv;
            s1 += y;
            s2 = fmaf(y, y, s2);
            bestx = fmaxf(bestx, y);
            bestn = fminf(bestn, y);
        }
        mx[(size_t)r * O + o] = bestx;
        mn[(size_t)r * O + o] = bestn;
    }
    partial[((size_t)blockIdx.x * 256 + tid) * 2 + 0] = s1;
    partial[((size_t)blockIdx.x * 256 + tid) * 2 + 1] = s2;
}

// reduce partials -> per-channel scale/shift.  grid = O blocks, 256 threads.
__global__ __launch_bounds__(256) void stats_reduce(const float* __restrict__ partial, int nblk,
                                                    int O, float cnt,
                                                    const float* __restrict__ g,
                                                    const float* __restrict__ bsh,
                                                    float* __restrict__ st) {
    __shared__ float r1[4], r2[4];
    int o = blockIdx.x, tid = threadIdx.x;
    int lanes = 256 / O;
    int total = nblk * lanes;
    float s1 = 0.f, s2 = 0.f;
    for (int t = tid; t < total; t += 256) {
        int blk = t / lanes, ps = t - blk * lanes;
        size_t base = ((size_t)blk * 256 + (size_t)ps * O + o) * 2;
        s1 += partial[base];
        s2 += partial[base + 1];
    }
    #pragma unroll
    for (int s = 32; s > 0; s >>= 1) {
        s1 += __shfl_down(s1, s, 64);
        s2 += __shfl_down(s2, s, 64);
    }
    if ((tid & 63) == 0) { r1[tid >> 6] = s1; r2[tid >> 6] = s2; }
    __syncthreads();
    if (tid == 0) {
        s1 = r1[0] + r1[1] + r1[2] + r1[3];
        s2 = r2[0] + r2[1] + r2[2] + r2[3];
        float mu = s1 / cnt;
        float var = s2 / cnt - mu * mu;
        float x = var + EPSB;
        float rr = rsqrtf(x);
        rr = rr * (1.5f - 0.5f * x * rr * rr);   // Newton refine
        float sc = g[o] * rr;
        st[o] = sc;
        st[O + o] = bsh[o] - mu * sc;
    }
}

// select max/min by scale sign, affine + LeakyReLU, write into xcat slice
__global__ void apply_edge(const float* __restrict__ mx, const float* __restrict__ mn,
                           const float* __restrict__ st, int O, int choff,
                           float* __restrict__ xcat) {
    int e = blockIdx.x * 256 + threadIdx.x;
    if (e >= PP * O) return;
    int r = e / O, o = e % O;
    float sc = st[o], tt = st[O + o];
    float base = (sc >= 0.f) ? mx[e] : mn[e];
    float y = fmaf(sc, base, tt);
    y = (y >= 0.f) ? y : LEAK * y;
    xcat[(size_t)r * 512 + choff + o] = y;
}

// ---------------------------------------------------------------------------
// Final BN stats over y5 (PP x 512)
__global__ __launch_bounds__(256) void final_stats(const float* __restrict__ y5,
                                                   float* __restrict__ partial) {
    int blk = blockIdx.x, t = threadIdx.x;
    float s1a = 0.f, s2a = 0.f, s1b = 0.f, s2b = 0.f;
    for (int rr = 0; rr < 128; ++rr) {
        size_t row = (size_t)(blk * 128 + rr) * 512;
        float va = y5[row + t], vb = y5[row + t + 256];
        s1a += va; s2a = fmaf(va, va, s2a);
        s1b += vb; s2b = fmaf(vb, vb, s2b);
    }
    partial[((size_t)blk * 512 + t) * 2 + 0] = s1a;
    partial[((size_t)blk * 512 + t) * 2 + 1] = s2a;
    partial[((size_t)blk * 512 + t + 256) * 2 + 0] = s1b;
    partial[((size_t)blk * 512 + t + 256) * 2 + 1] = s2b;
}

// grid = 512 blocks, 64 threads: one channel per block
__global__ __launch_bounds__(64) void final_reduce(const float* __restrict__ partial, int nblk,
                                                   float cnt,
                                                   const float* __restrict__ g,
                                                   const float* __restrict__ bsh,
                                                   float* __restrict__ st) {
    int c = blockIdx.x, tid = threadIdx.x;
    float s1 = 0.f, s2 = 0.f;
    for (int bk = tid; bk < nblk; bk += 64) {
        size_t base = ((size_t)bk * 512 + c) * 2;
        s1 += partial[base];
        s2 += partial[base + 1];
    }
    #pragma unroll
    for (int s = 32; s > 0; s >>= 1) {
        s1 += __shfl_down(s1, s, 64);
        s2 += __shfl_down(s2, s, 64);
    }
    if (tid == 0) {
        float mu = s1 / cnt;
        float var = s2 / cnt - mu * mu;
        float x = var + EPSB;
        float rr = rsqrtf(x);
        rr = rr * (1.5f - 0.5f * x * rr * rr);
        float sc = g[c] * rr;
        st[c] = sc;
        st[512 + c] = bsh[c] - mu * sc;
    }
}

// affine+lrelu + transpose (B,N,512) -> (B,512,N)
__global__ __launch_bounds__(256) void final_apply(const float* __restrict__ y5,
                                                   const float* __restrict__ st,
                                                   float* __restrict__ out) {
    __shared__ float tile[32][33];
    int n0 = blockIdx.x * 32, o0 = blockIdx.y * 32, b = blockIdx.z;
    int tx = threadIdx.x, ty = threadIdx.y;
    for (int i = 0; i < 4; ++i) {
        int nl = ty + i * 8;
        tile[nl][tx] = y5[((size_t)(b * NN + n0 + nl)) * 512 + o0 + tx];
    }
    __syncthreads();
    for (int i = 0; i < 4; ++i) {
        int ol = ty + i * 8;
        int o = o0 + ol;
        float sc = st[o], tt = st[512 + o];
        float yv = fmaf(sc, tile[tx][ol], tt);
        yv = (yv >= 0.f) ? yv : LEAK * yv;
        out[((size_t)b * 512 + o) * NN + n0 + tx] = yv;
    }
}

// ---------------------------------------------------------------------------
extern "C" void kernel_launch(void* const* d_in, const int* in_sizes, int n_in,
                              void* d_out, int out_size, void* d_ws, size_t ws_size,
                              hipStream_t stream) {
    const float* pts = (const float*)d_in[0];
    const float* w[5]; const float* g[5]; const float* bsh[5];
    for (int i = 0; i < 5; ++i) {
        w[i]   = (const float*)d_in[1 + 3 * i];
        g[i]   = (const float*)d_in[2 + 3 * i];
        bsh[i] = (const float*)d_in[3 + 3 * i];
    }
    float* out = (float*)d_out;

    // workspace layout
    float* xcat = (float*)d_ws;                  // PP*512
    float* u    = xcat + (size_t)PP * 512;       // PP*256
    float* v    = u    + (size_t)PP * 256;       // PP*256
    float* mxb  = v    + (size_t)PP * 256;       // PP*256
    float* mnb  = mxb  + (size_t)PP * 256;       // PP*256
    float* y5   = u;                             // overlay u+v (PP*512)
    float* ptst = mnb  + (size_t)PP * 256;       // PP*2
    int*   idxb = (int*)(ptst + (size_t)PP * 2); // PP*20
    float* part = (float*)(idxb + (size_t)PP * KK); // up to 512*256*2
    float* st   = part + (size_t)512 * 256 * 2;  // 1024

    transpose_pts<<<(PP + 255) / 256, 256, 0, stream>>>(pts, ptst);
    knn_kernel<<<PP, 256, 0, stream>>>(pts, idxb);

    const int Cs[4]    = {2, 64, 64, 128};
    const int Os[4]    = {64, 64, 128, 256};
    const int choffs[4]= {0, 64, 128, 256};
    const int inoffs[4]= {0, 0, 64, 128};

    for (int li = 0; li < 4; ++li) {
        const float* X  = (li == 0) ? ptst : (xcat + inoffs[li]);
        int ldx         = (li == 0) ? 2 : 512;
        int C = Cs[li], O = Os[li];
        dim3 gg(PP / 64, (2 * O) / 64);
        proj_gemm<<<gg, 256, 0, stream>>>(X, ldx, C, w[li], O, 0, u, v);
        edge_stats<<<PP / 16, 256, 0, stream>>>(u, v, idxb, O, mxb, mnb, part);
        stats_reduce<<<O, 256, 0, stream>>>(part, PP / 16, O, (float)((size_t)PP * KK),
                                            g[li], bsh[li], st);
        apply_edge<<<(PP * O + 255) / 256, 256, 0, stream>>>(mxb, mnb, st, O, choffs[li], xcat);
    }

    // final conv1d 512->512 + BN + lrelu, output transposed to (B,512,N)
    dim3 gf(PP / 64, 512 / 64);
    proj_gemm<<<gf, 256, 0, stream>>>(xcat, 512, 512, w[4], 512, 1, y5, nullptr);
    final_stats<<<64, 256, 0, stream>>>(y5, part);
    final_reduce<<<512, 64, 0, stream>>>(part, 64, (float)PP, g[4], bsh[4], st);
    final_apply<<<dim3(NN / 32, 512 / 32, BB), dim3(32, 8), 0, stream>>>(y5, st, out);
}

// Round 4
// 362.719 us; speedup vs baseline: 3.1242x; 1.2481x over previous
//
#include <hip/hip_runtime.h>
#include <hip/hip_bf16.h>
#include <math.h>

// Problem constants
#define BB 2
#define NN 4096
#define PP (BB*NN)      // 8192 points total
#define KK 20
#define LEAK 0.2f
#define EPSB 1e-5f

typedef short sv8 __attribute__((ext_vector_type(8)));   // 8 bf16 (4 VGPRs)
typedef float f4  __attribute__((ext_vector_type(4)));   // 4 fp32 acc

__device__ inline unsigned short f2bf(float f) {         // RNE fp32->bf16
    unsigned u = __float_as_uint(f);
    unsigned r = (u + 0x7FFFu + ((u >> 16) & 1u)) >> 16;
    return (unsigned short)r;
}
__device__ inline float bf2f(unsigned short h) {
    return __uint_as_float((unsigned)h << 16);
}
__device__ inline void gload16(const void* g, void* l) {
    __builtin_amdgcn_global_load_lds(
        (const __attribute__((address_space(1))) unsigned int*)g,
        (__attribute__((address_space(3))) unsigned int*)l, 16, 0, 0);
}

// ---------------------------------------------------------------------------
// transpose pts (B,2,N) -> (B,N,2)
__global__ void transpose_pts(const float* __restrict__ pts, float* __restrict__ pts_t) {
    int e = blockIdx.x * 256 + threadIdx.x;
    if (e >= PP) return;
    int b = e / NN, n = e % NN;
    pts_t[(size_t)e * 2 + 0] = pts[(size_t)b * 2 * NN + n];
    pts_t[(size_t)e * 2 + 1] = pts[(size_t)b * 2 * NN + NN + n];
}

// ---------------------------------------------------------------------------
// kNN v3: register-resident sort-then-merge (verified R3).
__global__ __launch_bounds__(256) void knn_kernel(const float* __restrict__ pts,
                                                  int* __restrict__ idx) {
    __shared__ unsigned long long wbuf[2][4];
    int r = blockIdx.x;            // b*N + n
    int b = r >> 12, n = r & (NN - 1);
    const float* X0 = pts + (size_t)b * 2 * NN;
    const float* X1 = X0 + NN;
    int tid = threadIdx.x;
    float x0n = X0[n], x1n = X1[n];
    float xxn = __fadd_rn(__fmul_rn(x0n, x0n), __fmul_rn(x1n, x1n));
    float negxxn = __fsub_rn(0.f, xxn);

    unsigned long long a[16];
    #pragma unroll
    for (int q = 0; q < 16; ++q) {
        int m = q * 256 + tid;
        float x0m = X0[m], x1m = X1[m];
        float xxm = __fadd_rn(__fmul_rn(x0m, x0m), __fmul_rn(x1m, x1m));
        float dot = __builtin_fmaf(x1n, x1m, __fmul_rn(x0n, x0m));
        float inner = __fmul_rn(-2.f, dot);
        float t1 = __fsub_rn(negxxn, inner);
        float pdv = __fsub_rn(t1, xxm);
        unsigned int ub = __float_as_uint(pdv);
        unsigned int fk = (ub & 0x80000000u) ? ~ub : (ub | 0x80000000u);
        a[q] = ((unsigned long long)fk << 32) | (unsigned int)(NN - 1 - m);
    }
    #pragma unroll
    for (int k = 2; k <= 16; k <<= 1) {
        #pragma unroll
        for (int j = k >> 1; j > 0; j >>= 1) {
            #pragma unroll
            for (int i = 0; i < 16; ++i) {
                int l = i ^ j;
                if (l > i) {
                    bool dir = ((i & k) == 0);
                    unsigned long long x = a[i], y = a[l];
                    bool sw = dir ? (x > y) : (x < y);
                    if (sw) { a[i] = y; a[l] = x; }
                }
            }
        }
    }
    int h = 15;
    unsigned long long hk = a[15];
    for (int k = 0; k < KK; ++k) {
        unsigned long long mk = hk;
        #pragma unroll
        for (int s = 32; s > 0; s >>= 1) {
            unsigned long long o = __shfl_xor(mk, s, 64);
            if (o > mk) mk = o;
        }
        if ((tid & 63) == 0) wbuf[k & 1][tid >> 6] = mk;
        __syncthreads();
        unsigned long long g0 = wbuf[k & 1][0], g1 = wbuf[k & 1][1];
        unsigned long long g2 = wbuf[k & 1][2], g3 = wbuf[k & 1][3];
        unsigned long long ga = g0 > g1 ? g0 : g1;
        unsigned long long gb = g2 > g3 ? g2 : g3;
        unsigned long long gm = ga > gb ? ga : gb;
        if (tid == 0) {
            int m = NN - 1 - (int)(gm & 0xFFFFFFFFu);
            idx[(size_t)r * KK + k] = m;
        }
        if (hk == gm) {
            --h;
            unsigned long long nk = 0ULL;
            #pragma unroll
            for (int t = 0; t < 15; ++t) nk = (h == t) ? a[t] : nk;
            hk = nk;
        }
    }
}

// ---------------------------------------------------------------------------
// fp32 projection GEMM (layer 1 only: K=2). mode 0 semantics as before.
__global__ __launch_bounds__(256) void proj_gemm(const float* __restrict__ X, int ldx, int C,
                                                 const float* __restrict__ W, int O, int mode,
                                                 float* __restrict__ outU, float* __restrict__ outV) {
    __shared__ float Xs[16][65];
    __shared__ float Ws[16][65];
    int row0 = blockIdx.x * 64, col0 = blockIdx.y * 64;
    int tid = threadIdx.x;
    int tx = tid % 16, ty = tid / 16;
    float acc[4][4] = {};
    for (int c0 = 0; c0 < C; c0 += 16) {
        for (int i = 0; i < 4; ++i) {
            int mm = ty + i * 16;
            float val = 0.f;
            if (c0 + tx < C) val = X[(size_t)(row0 + mm) * ldx + c0 + tx];
            Xs[tx][mm] = val;
        }
        for (int i = 0; i < 4; ++i) {
            int jj = ty + i * 16;
            int j = col0 + jj;
            float val = 0.f;
            if (c0 + tx < C) {
                if (mode == 0) {
                    if (j < O) val = W[(size_t)j * (2 * C) + c0 + tx];
                    else {
                        const float* wr = W + (size_t)(j - O) * (2 * C);
                        val = wr[C + c0 + tx] - wr[c0 + tx];
                    }
                } else {
                    val = W[(size_t)j * C + c0 + tx];
                }
            }
            Ws[tx][jj] = val;
        }
        __syncthreads();
        int kmax = (C - c0 < 16) ? (C - c0) : 16;
        for (int kk = 0; kk < kmax; ++kk) {
            float a[4], bw[4];
            #pragma unroll
            for (int i = 0; i < 4; ++i) a[i] = Xs[kk][ty * 4 + i];
            #pragma unroll
            for (int j = 0; j < 4; ++j) bw[j] = Ws[kk][tx * 4 + j];
            #pragma unroll
            for (int i = 0; i < 4; ++i)
                #pragma unroll
                for (int j = 0; j < 4; ++j)
                    acc[i][j] = fmaf(a[i], bw[j], acc[i][j]);
        }
        __syncthreads();
    }
    for (int i = 0; i < 4; ++i) {
        int rr = row0 + ty * 4 + i;
        for (int j = 0; j < 4; ++j) {
            int jg = col0 + tx * 4 + j;
            float vv = acc[i][j];
            if (mode == 0) {
                if (jg < O) outU[(size_t)rr * O + jg] = vv;
                else        outV[(size_t)rr * O + (jg - O)] = vv;
            } else {
                outU[(size_t)rr * O + jg] = vv;
            }
        }
    }
}

// ---------------------------------------------------------------------------
// Weight conversion: build Bmat rows (2O x C for mode0: [wA; wB-wA], O x C for
// mode1) and split into hi/lo bf16 planes.
__global__ void convert_w(const float* __restrict__ w, int O, int C, int mode,
                          unsigned short* __restrict__ bh, unsigned short* __restrict__ bl) {
    int total = (mode == 0 ? 2 * O : O) * C;
    int i = blockIdx.x * 256 + threadIdx.x;
    if (i >= total) return;
    int j = i / C, c = i - j * C;
    float v;
    if (mode == 0) {
        if (j < O) v = w[(size_t)j * 2 * C + c];
        else {
            const float* wr = w + (size_t)(j - O) * 2 * C;
            v = wr[C + c] - wr[c];
        }
    } else {
        v = w[(size_t)j * C + c];
    }
    unsigned short h = f2bf(v);
    bh[i] = h;
    bl[i] = f2bf(v - bf2f(h));
}

// ---------------------------------------------------------------------------
// Split-bf16 MFMA GEMM: out[p][j] = sum_c X[p][c] * Bm[j][c], X = Xh+Xl,
// Bm = Bh+Bl (drop lo*lo). Tile 128x128, 4 waves (2x2), wave tile 64x64,
// K-step 32, mfma_f32_16x16x32_bf16.
// LDS layout per tile: chunk index (kb*128 + row), 16B per chunk -> linear,
// staged via global_load_lds (wave-uniform LDS base + lane*16).
__global__ __launch_bounds__(256) void mfma_gemm(const unsigned short* __restrict__ Xh,
                                                 const unsigned short* __restrict__ Xl, int ldx,
                                                 int K,
                                                 const unsigned short* __restrict__ Bh,
                                                 const unsigned short* __restrict__ Bl,
                                                 int O, int mode,
                                                 float* __restrict__ outU,
                                                 float* __restrict__ outV) {
    __shared__ unsigned short Ah[512 * 8], Al[512 * 8], Bhs[512 * 8], Bls[512 * 8];
    int row0 = blockIdx.x * 128, col0 = blockIdx.y * 128;
    int tid = threadIdx.x;
    int wid = tid >> 6, lane = tid & 63;
    int wm = wid & 1, wn = wid >> 1;
    int l15 = lane & 15, l4 = lane >> 4;

    f4 acc[4][4];
    #pragma unroll
    for (int i = 0; i < 4; ++i)
        #pragma unroll
        for (int j = 0; j < 4; ++j) { acc[i][j][0]=0.f; acc[i][j][1]=0.f; acc[i][j][2]=0.f; acc[i][j][3]=0.f; }

    for (int k0 = 0; k0 < K; k0 += 32) {
        // stage A and B tiles (hi+lo): 512 16B-chunks each plane, 2 per thread
        #pragma unroll
        for (int j = 0; j < 2; ++j) {
            int c = tid + 256 * j;
            int m = c & 127, kb = c >> 7;
            unsigned short* lbase_a = &Ah[(size_t)(wid * 64 + 256 * j) * 8];
            unsigned short* lbase_b = &Bhs[(size_t)(wid * 64 + 256 * j) * 8];
            size_t ga = (size_t)(row0 + m) * ldx + k0 + kb * 8;
            size_t gb = (size_t)(col0 + m) * K + k0 + kb * 8;
            gload16(Xh + ga, lbase_a);
            gload16(Xl + ga, &Al[(size_t)(wid * 64 + 256 * j) * 8]);
            gload16(Bh + gb, lbase_b);
            gload16(Bl + gb, &Bls[(size_t)(wid * 64 + 256 * j) * 8]);
        }
        __syncthreads();   // drains vmcnt -> gload_lds complete

        sv8 bhf[4], blf[4];
        #pragma unroll
        for (int fn = 0; fn < 4; ++fn) {
            int n = wn * 64 + fn * 16 + l15;
            bhf[fn] = *(const sv8*)&Bhs[(size_t)(l4 * 128 + n) * 8];
            blf[fn] = *(const sv8*)&Bls[(size_t)(l4 * 128 + n) * 8];
        }
        #pragma unroll
        for (int fm = 0; fm < 4; ++fm) {
            int m = wm * 64 + fm * 16 + l15;
            sv8 ah = *(const sv8*)&Ah[(size_t)(l4 * 128 + m) * 8];
            sv8 al = *(const sv8*)&Al[(size_t)(l4 * 128 + m) * 8];
            #pragma unroll
            for (int fn = 0; fn < 4; ++fn) {
                acc[fm][fn] = __builtin_amdgcn_mfma_f32_16x16x32_bf16(ah, bhf[fn], acc[fm][fn], 0, 0, 0);
                acc[fm][fn] = __builtin_amdgcn_mfma_f32_16x16x32_bf16(ah, blf[fn], acc[fm][fn], 0, 0, 0);
                acc[fm][fn] = __builtin_amdgcn_mfma_f32_16x16x32_bf16(al, bhf[fn], acc[fm][fn], 0, 0, 0);
            }
        }
        __syncthreads();   // protect LDS before next stage
    }

    // C/D layout: col = lane&15, row = (lane>>4)*4 + e  [m89 verified]
    #pragma unroll
    for (int fm = 0; fm < 4; ++fm) {
        int rbase = row0 + wm * 64 + fm * 16 + l4 * 4;
        #pragma unroll
        for (int fn = 0; fn < 4; ++fn) {
            int jg = col0 + wn * 64 + fn * 16 + l15;
            #pragma unroll
            for (int e = 0; e < 4; ++e) {
                float vv = acc[fm][fn][e];
                int p = rbase + e;
                if (mode == 1 || jg < O) outU[(size_t)p * O + jg] = vv;
                else                     outV[(size_t)p * O + (jg - O)] = vv;
            }
        }
    }
}

// ---------------------------------------------------------------------------
// Per-point gather + per-channel sum/sumsq partials + per-(point,channel) max/min over K
__global__ __launch_bounds__(256) void edge_stats(const float* __restrict__ u,
                                                  const float* __restrict__ v,
                                                  const int* __restrict__ idx,
                                                  int O,
                                                  float* __restrict__ mx, float* __restrict__ mn,
                                                  float* __restrict__ partial) {
    const int PTS = 16;
    int tid = threadIdx.x;
    int lanes = 256 / O;
    int o = tid % O, ps = tid / O;
    int ppl = PTS / lanes;
    int r0 = blockIdx.x * PTS;
    float s1 = 0.f, s2 = 0.f;
    for (int pi = 0; pi < ppl; ++pi) {
        int r = r0 + ps * ppl + pi;
        int b = r / NN;
        float vv = v[(size_t)r * O + o];
        const int* ip = idx + (size_t)r * KK;
        float bestx = -INFINITY, bestn = INFINITY;
        const float* ub = u + (size_t)b * NN * O;
        #pragma unroll 4
        for (int k = 0; k < KK; ++k) {
            int m = ip[k];
            float y = ub[(size_t)m * O + o] + vv;
            s1 += y;
            s2 = fmaf(y, y, s2);
            bestx = fmaxf(bestx, y);
            bestn = fminf(bestn, y);
        }
        mx[(size_t)r * O + o] = bestx;
        mn[(size_t)r * O + o] = bestn;
    }
    partial[((size_t)blockIdx.x * 256 + tid) * 2 + 0] = s1;
    partial[((size_t)blockIdx.x * 256 + tid) * 2 + 1] = s2;
}

// reduce partials -> per-channel scale/shift.  grid = O blocks, 256 threads.
__global__ __launch_bounds__(256) void stats_reduce(const float* __restrict__ partial, int nblk,
                                                    int O, float cnt,
                                                    const float* __restrict__ g,
                                                    const float* __restrict__ bsh,
                                                    float* __restrict__ st) {
    __shared__ float r1[4], r2[4];
    int o = blockIdx.x, tid = threadIdx.x;
    int lanes = 256 / O;
    int total = nblk * lanes;
    float s1 = 0.f, s2 = 0.f;
    for (int t = tid; t < total; t += 256) {
        int blk = t / lanes, ps = t - blk * lanes;
        size_t base = ((size_t)blk * 256 + (size_t)ps * O + o) * 2;
        s1 += partial[base];
        s2 += partial[base + 1];
    }
    #pragma unroll
    for (int s = 32; s > 0; s >>= 1) {
        s1 += __shfl_down(s1, s, 64);
        s2 += __shfl_down(s2, s, 64);
    }
    if ((tid & 63) == 0) { r1[tid >> 6] = s1; r2[tid >> 6] = s2; }
    __syncthreads();
    if (tid == 0) {
        s1 = r1[0] + r1[1] + r1[2] + r1[3];
        s2 = r2[0] + r2[1] + r2[2] + r2[3];
        float mu = s1 / cnt;
        float var = s2 / cnt - mu * mu;
        float x = var + EPSB;
        float rr = rsqrtf(x);
        rr = rr * (1.5f - 0.5f * x * rr * rr);
        float sc = g[o] * rr;
        st[o] = sc;
        st[O + o] = bsh[o] - mu * sc;
    }
}

// select max/min by scale sign, affine + LeakyReLU, write hi/lo bf16 planes
__global__ void apply_edge(const float* __restrict__ mx, const float* __restrict__ mn,
                           const float* __restrict__ st, int O, int choff,
                           unsigned short* __restrict__ xh, unsigned short* __restrict__ xl) {
    int e = blockIdx.x * 256 + threadIdx.x;
    if (e >= PP * O) return;
    int r = e / O, o = e % O;
    float sc = st[o], tt = st[O + o];
    float base = (sc >= 0.f) ? mx[e] : mn[e];
    float y = fmaf(sc, base, tt);
    y = (y >= 0.f) ? y : LEAK * y;
    unsigned short h = f2bf(y);
    size_t d = (size_t)r * 512 + choff + o;
    xh[d] = h;
    xl[d] = f2bf(y - bf2f(h));
}

// ---------------------------------------------------------------------------
// Final BN stats over y5 (PP x 512)
__global__ __launch_bounds__(256) void final_stats(const float* __restrict__ y5,
                                                   float* __restrict__ partial) {
    int blk = blockIdx.x, t = threadIdx.x;
    float s1a = 0.f, s2a = 0.f, s1b = 0.f, s2b = 0.f;
    for (int rr = 0; rr < 128; ++rr) {
        size_t row = (size_t)(blk * 128 + rr) * 512;
        float va = y5[row + t], vb = y5[row + t + 256];
        s1a += va; s2a = fmaf(va, va, s2a);
        s1b += vb; s2b = fmaf(vb, vb, s2b);
    }
    partial[((size_t)blk * 512 + t) * 2 + 0] = s1a;
    partial[((size_t)blk * 512 + t) * 2 + 1] = s2a;
    partial[((size_t)blk * 512 + t + 256) * 2 + 0] = s1b;
    partial[((size_t)blk * 512 + t + 256) * 2 + 1] = s2b;
}

// grid = 512 blocks, 64 threads: one channel per block
__global__ __launch_bounds__(64) void final_reduce(const float* __restrict__ partial, int nblk,
                                                   float cnt,
                                                   const float* __restrict__ g,
                                                   const float* __restrict__ bsh,
                                                   float* __restrict__ st) {
    int c = blockIdx.x, tid = threadIdx.x;
    float s1 = 0.f, s2 = 0.f;
    for (int bk = tid; bk < nblk; bk += 64) {
        size_t base = ((size_t)bk * 512 + c) * 2;
        s1 += partial[base];
        s2 += partial[base + 1];
    }
    #pragma unroll
    for (int s = 32; s > 0; s >>= 1) {
        s1 += __shfl_down(s1, s, 64);
        s2 += __shfl_down(s2, s, 64);
    }
    if (tid == 0) {
        float mu = s1 / cnt;
        float var = s2 / cnt - mu * mu;
        float x = var + EPSB;
        float rr = rsqrtf(x);
        rr = rr * (1.5f - 0.5f * x * rr * rr);
        float sc = g[c] * rr;
        st[c] = sc;
        st[512 + c] = bsh[c] - mu * sc;
    }
}

// affine+lrelu + transpose (B,N,512) -> (B,512,N)
__global__ __launch_bounds__(256) void final_apply(const float* __restrict__ y5,
                                                   const float* __restrict__ st,
                                                   float* __restrict__ out) {
    __shared__ float tile[32][33];
    int n0 = blockIdx.x * 32, o0 = blockIdx.y * 32, b = blockIdx.z;
    int tx = threadIdx.x, ty = threadIdx.y;
    for (int i = 0; i < 4; ++i) {
        int nl = ty + i * 8;
        tile[nl][tx] = y5[((size_t)(b * NN + n0 + nl)) * 512 + o0 + tx];
    }
    __syncthreads();
    for (int i = 0; i < 4; ++i) {
        int ol = ty + i * 8;
        int o = o0 + ol;
        float sc = st[o], tt = st[512 + o];
        float yv = fmaf(sc, tile[tx][ol], tt);
        yv = (yv >= 0.f) ? yv : LEAK * yv;
        out[((size_t)b * 512 + o) * NN + n0 + tx] = yv;
    }
}

// ---------------------------------------------------------------------------
extern "C" void kernel_launch(void* const* d_in, const int* in_sizes, int n_in,
                              void* d_out, int out_size, void* d_ws, size_t ws_size,
                              hipStream_t stream) {
    const float* pts = (const float*)d_in[0];
    const float* w[5]; const float* g[5]; const float* bsh[5];
    for (int i = 0; i < 5; ++i) {
        w[i]   = (const float*)d_in[1 + 3 * i];
        g[i]   = (const float*)d_in[2 + 3 * i];
        bsh[i] = (const float*)d_in[3 + 3 * i];
    }
    float* out = (float*)d_out;

    // workspace layout (floats unless noted)
    unsigned short* xh = (unsigned short*)d_ws;              // PP*512 bf16 hi
    unsigned short* xl = xh + (size_t)PP * 512;              // PP*512 bf16 lo
    float* u    = (float*)(xl + (size_t)PP * 512);           // PP*256
    float* v    = u    + (size_t)PP * 256;                   // PP*256
    float* mxb  = v    + (size_t)PP * 256;                   // PP*256
    float* mnb  = mxb  + (size_t)PP * 256;                   // PP*256
    float* y5   = u;                                         // overlay u+v (PP*512)
    float* ptst = mnb  + (size_t)PP * 256;                   // PP*2
    int*   idxb = (int*)(ptst + (size_t)PP * 2);             // PP*20
    float* part = (float*)(idxb + (size_t)PP * KK);          // 512*256*2 floats (1MB)
    float* st   = part + (size_t)512 * 256 * 2;              // 1024
    // bh/bl overlay part (sequenced: convert+gemm finish before stats write part)
    unsigned short* bmh = (unsigned short*)part;             // up to 512*512
    unsigned short* bml = bmh + (size_t)512 * 512;

    transpose_pts<<<(PP + 255) / 256, 256, 0, stream>>>(pts, ptst);
    knn_kernel<<<PP, 256, 0, stream>>>(pts, idxb);

    const int Cs[4]    = {2, 64, 64, 128};
    const int Os[4]    = {64, 64, 128, 256};
    const int choffs[4]= {0, 64, 128, 256};
    const int inoffs[4]= {0, 0, 64, 128};

    for (int li = 0; li < 4; ++li) {
        int C = Cs[li], O = Os[li];
        if (li == 0) {
            dim3 gg(PP / 64, (2 * O) / 64);
            proj_gemm<<<gg, 256, 0, stream>>>(ptst, 2, C, w[li], O, 0, u, v);
        } else {
            int total = 2 * O * C;
            convert_w<<<(total + 255) / 256, 256, 0, stream>>>(w[li], O, C, 0, bmh, bml);
            dim3 gg(PP / 128, (2 * O) / 128);
            mfma_gemm<<<gg, 256, 0, stream>>>(xh + inoffs[li], xl + inoffs[li], 512, C,
                                              bmh, bml, O, 0, u, v);
        }
        edge_stats<<<PP / 16, 256, 0, stream>>>(u, v, idxb, O, mxb, mnb, part);
        stats_reduce<<<O, 256, 0, stream>>>(part, PP / 16, O, (float)((size_t)PP * KK),
                                            g[li], bsh[li], st);
        apply_edge<<<(PP * O + 255) / 256, 256, 0, stream>>>(mxb, mnb, st, O, choffs[li], xh, xl);
    }

    // final conv1d 512->512 (split-bf16 MFMA) + BN + lrelu, transposed output
    convert_w<<<(512 * 512 + 255) / 256, 256, 0, stream>>>(w[4], 512, 512, 1, bmh, bml);
    dim3 gf(PP / 128, 512 / 128);
    mfma_gemm<<<gf, 256, 0, stream>>>(xh, xl, 512, 512, bmh, bml, 512, 1, y5, nullptr);
    final_stats<<<64, 256, 0, stream>>>(y5, part);
    final_reduce<<<512, 64, 0, stream>>>(part, 64, (float)PP, g[4], bsh[4], st);
    final_apply<<<dim3(NN / 32, 512 / 32, BB), dim3(32, 8), 0, stream>>>(y5, st, out);
}

// Round 5
// 291.456 us; speedup vs baseline: 3.8881x; 1.2445x over previous
//
#include <hip/hip_runtime.h>
#include <hip/hip_bf16.h>
#include <math.h>

// Problem constants
#define BB 2
#define NN 4096
#define PP (BB*NN)      // 8192 points total
#define KK 20
#define LEAK 0.2f
#define EPSB 1e-5f

typedef short sv8 __attribute__((ext_vector_type(8)));   // 8 bf16 (4 VGPRs)
typedef float f4  __attribute__((ext_vector_type(4)));   // 4 fp32 acc

__device__ inline unsigned short f2bf(float f) {         // RNE fp32->bf16
    unsigned u = __float_as_uint(f);
    unsigned r = (u + 0x7FFFu + ((u >> 16) & 1u)) >> 16;
    return (unsigned short)r;
}
__device__ inline float bf2f(unsigned short h) {
    return __uint_as_float((unsigned)h << 16);
}
__device__ inline void gload16(const void* g, void* l) {
    __builtin_amdgcn_global_load_lds(
        (const __attribute__((address_space(1))) unsigned int*)g,
        (__attribute__((address_space(3))) unsigned int*)l, 16, 0, 0);
}

// ---------------------------------------------------------------------------
// transpose pts (B,2,N) -> (B,N,2)
__global__ void transpose_pts(const float* __restrict__ pts, float* __restrict__ pts_t) {
    int e = blockIdx.x * 256 + threadIdx.x;
    if (e >= PP) return;
    int b = e / NN, n = e % NN;
    pts_t[(size_t)e * 2 + 0] = pts[(size_t)b * 2 * NN + n];
    pts_t[(size_t)e * 2 + 1] = pts[(size_t)b * 2 * NN + NN + n];
}

// ---------------------------------------------------------------------------
// kNN v4: histogram radix-select (set-only semantics).
// idx is consumed only by order-invariant reductions (sum/max/min over K), so
// we emit the exact top-20 SET (jax tie rule: equal pd -> lower index) in
// arbitrary order. Exact pd arithmetic identical to verified R1-R4.
// Monotone fixed-point key s=max(-pd,0), ki=u32(s*2^shift), bin=ki>>16:
// bins < b* are definite members (strict monotone); bin b* resolved by exact
// (pd-bits, index) u64 compare via a short wave min-pop loop.
__global__ __launch_bounds__(256) void knn_kernel(const float* __restrict__ pts,
                                                  int* __restrict__ idx) {
    __shared__ unsigned int hist[256];
    __shared__ unsigned int scanres[3];   // found, bstar, cum_before
    __shared__ unsigned int cnt2[2];      // def count, boundary count
    __shared__ unsigned long long blist[512];

    int r = blockIdx.x;            // b*N + n
    int b = r >> 12, n = r & (NN - 1);
    const float* X0 = pts + (size_t)b * 2 * NN;
    const float* X1 = X0 + NN;
    int tid = threadIdx.x;
    float x0n = X0[n], x1n = X1[n];
    float xxn = __fadd_rn(__fmul_rn(x0n, x0n), __fmul_rn(x1n, x1n));
    float negxxn = __fsub_rn(0.f, xxn);

    float pdv[16];
    #pragma unroll
    for (int q = 0; q < 16; ++q) {
        int m = q * 256 + tid;
        float x0m = X0[m], x1m = X1[m];
        float xxm = __fadd_rn(__fmul_rn(x0m, x0m), __fmul_rn(x1m, x1m));
        float dot = __builtin_fmaf(x1n, x1m, __fmul_rn(x0n, x0m));
        float inner = __fmul_rn(-2.f, dot);
        float t1 = __fsub_rn(negxxn, inner);
        pdv[q] = __fsub_rn(t1, xxm);
    }

    // ---- find boundary bin via 256-bin histogram, scale fallback 24/18/12
    int shift = 24;
    for (int attempt = 0; attempt < 3; ++attempt) {
        hist[tid] = 0;
        __syncthreads();
        float scale = (float)(1u << shift);
        #pragma unroll
        for (int q = 0; q < 16; ++q) {
            float s = fmaxf(-pdv[q], 0.f);
            unsigned int ki = (unsigned int)fminf(s * scale, 4.294e9f);
            unsigned int bin = ki >> 16;
            if (bin < 255u) atomicAdd(&hist[bin], 1u);
        }
        __syncthreads();
        if (tid < 64) {
            uint4 hv = *(const uint4*)&hist[tid * 4];
            unsigned int p0 = hv.x, p1 = p0 + hv.y, p2 = p1 + hv.z, p3 = p2 + hv.w;
            unsigned int lanesum = p3, inc = p3;
            #pragma unroll
            for (int s2 = 1; s2 < 64; s2 <<= 1) {
                unsigned int o = __shfl_up(inc, s2, 64);
                if (tid >= s2) inc += o;
            }
            unsigned int excl = inc - lanesum;
            bool flag = (inc >= KK);
            unsigned long long bal = __ballot(flag);
            int firstlane = (bal == 0ULL) ? -1 : (__ffsll((long long)bal) - 1);
            if (tid == 0) scanres[0] = (bal != 0ULL) ? 1u : 0u;
            if (tid == firstlane) {
                unsigned int c0 = excl + p0, c1 = excl + p1, c2 = excl + p2;
                int t = (c0 >= KK) ? 0 : (c1 >= KK) ? 1 : (c2 >= KK) ? 2 : 3;
                unsigned int cumb = (t == 0) ? excl : (t == 1) ? c0 : (t == 2) ? c1 : c2;
                scanres[1] = (unsigned)(tid * 4 + t);
                scanres[2] = cumb;
            }
        }
        __syncthreads();
        if (scanres[0]) break;
        shift -= 6;
        __syncthreads();
    }

    unsigned int bstar = scanres[1];
    unsigned int cumb  = scanres[2];
    if (tid == 0) { cnt2[0] = 0; cnt2[1] = 0; }
    __syncthreads();

    // ---- classify and emit
    float scale = (float)(1u << shift);
    #pragma unroll
    for (int q = 0; q < 16; ++q) {
        float s = fmaxf(-pdv[q], 0.f);
        unsigned int ki = (unsigned int)fminf(s * scale, 4.294e9f);
        unsigned int bin = ki >> 16;
        if (bin > 255u) bin = 255u;
        int m = q * 256 + tid;
        if (bin < bstar) {
            unsigned int slot = atomicAdd(&cnt2[0], 1u);
            idx[(size_t)r * KK + slot] = m;
        } else if (bin == bstar) {
            unsigned int pos = atomicAdd(&cnt2[1], 1u);
            if (pos < 512u) {
                unsigned int ub = __float_as_uint(pdv[q]);
                unsigned int fk = (ub & 0x80000000u) ? ~ub : (ub | 0x80000000u);
                blist[pos] = ((unsigned long long)(~fk) << 32) | (unsigned int)m;
            }
        }
    }
    __syncthreads();

    // ---- boundary resolution: need = 20 - cumb smallest exact keys of blist
    int need = KK - (int)cumb;
    int L = (int)min(cnt2[1], 512u);
    if (tid < 64) {
        unsigned long long e[8];
        #pragma unroll
        for (int i = 0; i < 8; ++i) {
            int p = tid + 64 * i;
            e[i] = (p < L) ? blist[p] : ~0ULL;
        }
        unsigned long long lmin = e[0];
        #pragma unroll
        for (int i = 1; i < 8; ++i) lmin = (e[i] < lmin) ? e[i] : lmin;
        for (int p = 0; p < need; ++p) {
            unsigned long long gm = lmin;
            #pragma unroll
            for (int s2 = 32; s2 > 0; s2 >>= 1) {
                unsigned long long o = __shfl_xor(gm, s2, 64);
                if (o < gm) gm = o;
            }
            if (lmin == gm) {      // unique winner (keys unique)
                #pragma unroll
                for (int i = 0; i < 8; ++i) if (e[i] == gm) e[i] = ~0ULL;
                lmin = e[0];
                #pragma unroll
                for (int i = 1; i < 8; ++i) lmin = (e[i] < lmin) ? e[i] : lmin;
                idx[(size_t)r * KK + cumb + p] = (int)(gm & 0xFFFFFFFFu);
            }
        }
    }
}

// ---------------------------------------------------------------------------
// fp32 projection GEMM (layer 1 only: K=2). mode 0 semantics as before.
__global__ __launch_bounds__(256) void proj_gemm(const float* __restrict__ X, int ldx, int C,
                                                 const float* __restrict__ W, int O, int mode,
                                                 float* __restrict__ outU, float* __restrict__ outV) {
    __shared__ float Xs[16][65];
    __shared__ float Ws[16][65];
    int row0 = blockIdx.x * 64, col0 = blockIdx.y * 64;
    int tid = threadIdx.x;
    int tx = tid % 16, ty = tid / 16;
    float acc[4][4] = {};
    for (int c0 = 0; c0 < C; c0 += 16) {
        for (int i = 0; i < 4; ++i) {
            int mm = ty + i * 16;
            float val = 0.f;
            if (c0 + tx < C) val = X[(size_t)(row0 + mm) * ldx + c0 + tx];
            Xs[tx][mm] = val;
        }
        for (int i = 0; i < 4; ++i) {
            int jj = ty + i * 16;
            int j = col0 + jj;
            float val = 0.f;
            if (c0 + tx < C) {
                if (mode == 0) {
                    if (j < O) val = W[(size_t)j * (2 * C) + c0 + tx];
                    else {
                        const float* wr = W + (size_t)(j - O) * (2 * C);
                        val = wr[C + c0 + tx] - wr[c0 + tx];
                    }
                } else {
                    val = W[(size_t)j * C + c0 + tx];
                }
            }
            Ws[tx][jj] = val;
        }
        __syncthreads();
        int kmax = (C - c0 < 16) ? (C - c0) : 16;
        for (int kk = 0; kk < kmax; ++kk) {
            float a[4], bw[4];
            #pragma unroll
            for (int i = 0; i < 4; ++i) a[i] = Xs[kk][ty * 4 + i];
            #pragma unroll
            for (int j = 0; j < 4; ++j) bw[j] = Ws[kk][tx * 4 + j];
            #pragma unroll
            for (int i = 0; i < 4; ++i)
                #pragma unroll
                for (int j = 0; j < 4; ++j)
                    acc[i][j] = fmaf(a[i], bw[j], acc[i][j]);
        }
        __syncthreads();
    }
    for (int i = 0; i < 4; ++i) {
        int rr = row0 + ty * 4 + i;
        for (int j = 0; j < 4; ++j) {
            int jg = col0 + tx * 4 + j;
            float vv = acc[i][j];
            if (mode == 0) {
                if (jg < O) outU[(size_t)rr * O + jg] = vv;
                else        outV[(size_t)rr * O + (jg - O)] = vv;
            } else {
                outU[(size_t)rr * O + jg] = vv;
            }
        }
    }
}

// ---------------------------------------------------------------------------
// Weight conversion: build Bmat rows and split into hi/lo bf16 planes.
__global__ void convert_w(const float* __restrict__ w, int O, int C, int mode,
                          unsigned short* __restrict__ bh, unsigned short* __restrict__ bl) {
    int total = (mode == 0 ? 2 * O : O) * C;
    int i = blockIdx.x * 256 + threadIdx.x;
    if (i >= total) return;
    int j = i / C, c = i - j * C;
    float v;
    if (mode == 0) {
        if (j < O) v = w[(size_t)j * 2 * C + c];
        else {
            const float* wr = w + (size_t)(j - O) * 2 * C;
            v = wr[C + c] - wr[c];
        }
    } else {
        v = w[(size_t)j * C + c];
    }
    unsigned short h = f2bf(v);
    bh[i] = h;
    bl[i] = f2bf(v - bf2f(h));
}

// ---------------------------------------------------------------------------
// Split-bf16 MFMA GEMM (verified R4): out = (Xh+Xl)·(Bh+Bl)^T, drop lo*lo.
__global__ __launch_bounds__(256) void mfma_gemm(const unsigned short* __restrict__ Xh,
                                                 const unsigned short* __restrict__ Xl, int ldx,
                                                 int K,
                                                 const unsigned short* __restrict__ Bh,
                                                 const unsigned short* __restrict__ Bl,
                                                 int O, int mode,
                                                 float* __restrict__ outU,
                                                 float* __restrict__ outV) {
    __shared__ unsigned short Ah[512 * 8], Al[512 * 8], Bhs[512 * 8], Bls[512 * 8];
    int row0 = blockIdx.x * 128, col0 = blockIdx.y * 128;
    int tid = threadIdx.x;
    int wid = tid >> 6, lane = tid & 63;
    int wm = wid & 1, wn = wid >> 1;
    int l15 = lane & 15, l4 = lane >> 4;

    f4 acc[4][4];
    #pragma unroll
    for (int i = 0; i < 4; ++i)
        #pragma unroll
        for (int j = 0; j < 4; ++j) { acc[i][j][0]=0.f; acc[i][j][1]=0.f; acc[i][j][2]=0.f; acc[i][j][3]=0.f; }

    for (int k0 = 0; k0 < K; k0 += 32) {
        #pragma unroll
        for (int j = 0; j < 2; ++j) {
            int c = tid + 256 * j;
            int m = c & 127, kb = c >> 7;
            size_t ga = (size_t)(row0 + m) * ldx + k0 + kb * 8;
            size_t gb = (size_t)(col0 + m) * K + k0 + kb * 8;
            gload16(Xh + ga, &Ah[(size_t)(wid * 64 + 256 * j) * 8]);
            gload16(Xl + ga, &Al[(size_t)(wid * 64 + 256 * j) * 8]);
            gload16(Bh + gb, &Bhs[(size_t)(wid * 64 + 256 * j) * 8]);
            gload16(Bl + gb, &Bls[(size_t)(wid * 64 + 256 * j) * 8]);
        }
        __syncthreads();

        sv8 bhf[4], blf[4];
        #pragma unroll
        for (int fn = 0; fn < 4; ++fn) {
            int nn2 = wn * 64 + fn * 16 + l15;
            bhf[fn] = *(const sv8*)&Bhs[(size_t)(l4 * 128 + nn2) * 8];
            blf[fn] = *(const sv8*)&Bls[(size_t)(l4 * 128 + nn2) * 8];
        }
        #pragma unroll
        for (int fm = 0; fm < 4; ++fm) {
            int m = wm * 64 + fm * 16 + l15;
            sv8 ah = *(const sv8*)&Ah[(size_t)(l4 * 128 + m) * 8];
            sv8 al = *(const sv8*)&Al[(size_t)(l4 * 128 + m) * 8];
            #pragma unroll
            for (int fn = 0; fn < 4; ++fn) {
                acc[fm][fn] = __builtin_amdgcn_mfma_f32_16x16x32_bf16(ah, bhf[fn], acc[fm][fn], 0, 0, 0);
                acc[fm][fn] = __builtin_amdgcn_mfma_f32_16x16x32_bf16(ah, blf[fn], acc[fm][fn], 0, 0, 0);
                acc[fm][fn] = __builtin_amdgcn_mfma_f32_16x16x32_bf16(al, bhf[fn], acc[fm][fn], 0, 0, 0);
            }
        }
        __syncthreads();
    }

    #pragma unroll
    for (int fm = 0; fm < 4; ++fm) {
        int rbase = row0 + wm * 64 + fm * 16 + l4 * 4;
        #pragma unroll
        for (int fn = 0; fn < 4; ++fn) {
            int jg = col0 + wn * 64 + fn * 16 + l15;
            #pragma unroll
            for (int e = 0; e < 4; ++e) {
                float vv = acc[fm][fn][e];
                int p = rbase + e;
                if (mode == 1 || jg < O) outU[(size_t)p * O + jg] = vv;
                else                     outV[(size_t)p * O + (jg - O)] = vv;
            }
        }
    }
}

// ---------------------------------------------------------------------------
// Per-point gather + per-channel sum/sumsq partials + per-(point,channel) max/min over K
__global__ __launch_bounds__(256) void edge_stats(const float* __restrict__ u,
                                                  const float* __restrict__ v,
                                                  const int* __restrict__ idx,
                                                  int O,
                                                  float* __restrict__ mx, float* __restrict__ mn,
                                                  float* __restrict__ partial) {
    const int PTS = 16;
    int tid = threadIdx.x;
    int lanes = 256 / O;
    int o = tid % O, ps = tid / O;
    int ppl = PTS / lanes;
    int r0 = blockIdx.x * PTS;
    float s1 = 0.f, s2 = 0.f;
    for (int pi = 0; pi < ppl; ++pi) {
        int r = r0 + ps * ppl + pi;
        int b = r / NN;
        float vv = v[(size_t)r * O + o];
        const int* ip = idx + (size_t)r * KK;
        float bestx = -INFINITY, bestn = INFINITY;
        const float* ub = u + (size_t)b * NN * O;
        #pragma unroll 4
        for (int k = 0; k < KK; ++k) {
            int m = ip[k];
            float y = ub[(size_t)m * O + o] + vv;
            s1 += y;
            s2 = fmaf(y, y, s2);
            bestx = fmaxf(bestx, y);
            bestn = fminf(bestn, y);
        }
        mx[(size_t)r * O + o] = bestx;
        mn[(size_t)r * O + o] = bestn;
    }
    partial[((size_t)blockIdx.x * 256 + tid) * 2 + 0] = s1;
    partial[((size_t)blockIdx.x * 256 + tid) * 2 + 1] = s2;
}

// reduce partials -> per-channel scale/shift.  grid = O blocks, 256 threads.
__global__ __launch_bounds__(256) void stats_reduce(const float* __restrict__ partial, int nblk,
                                                    int O, float cnt,
                                                    const float* __restrict__ g,
                                                    const float* __restrict__ bsh,
                                                    float* __restrict__ st) {
    __shared__ float r1[4], r2[4];
    int o = blockIdx.x, tid = threadIdx.x;
    int lanes = 256 / O;
    int total = nblk * lanes;
    float s1 = 0.f, s2 = 0.f;
    for (int t = tid; t < total; t += 256) {
        int blk = t / lanes, ps = t - blk * lanes;
        size_t base = ((size_t)blk * 256 + (size_t)ps * O + o) * 2;
        s1 += partial[base];
        s2 += partial[base + 1];
    }
    #pragma unroll
    for (int s = 32; s > 0; s >>= 1) {
        s1 += __shfl_down(s1, s, 64);
        s2 += __shfl_down(s2, s, 64);
    }
    if ((tid & 63) == 0) { r1[tid >> 6] = s1; r2[tid >> 6] = s2; }
    __syncthreads();
    if (tid == 0) {
        s1 = r1[0] + r1[1] + r1[2] + r1[3];
        s2 = r2[0] + r2[1] + r2[2] + r2[3];
        float mu = s1 / cnt;
        float var = s2 / cnt - mu * mu;
        float x = var + EPSB;
        float rr = rsqrtf(x);
        rr = rr * (1.5f - 0.5f * x * rr * rr);
        float sc = g[o] * rr;
        st[o] = sc;
        st[O + o] = bsh[o] - mu * sc;
    }
}

// select max/min by scale sign, affine + LeakyReLU, write hi/lo bf16 planes
__global__ void apply_edge(const float* __restrict__ mx, const float* __restrict__ mn,
                           const float* __restrict__ st, int O, int choff,
                           unsigned short* __restrict__ xh, unsigned short* __restrict__ xl) {
    int e = blockIdx.x * 256 + threadIdx.x;
    if (e >= PP * O) return;
    int r = e / O, o = e % O;
    float sc = st[o], tt = st[O + o];
    float base = (sc >= 0.f) ? mx[e] : mn[e];
    float y = fmaf(sc, base, tt);
    y = (y >= 0.f) ? y : LEAK * y;
    unsigned short h = f2bf(y);
    size_t d = (size_t)r * 512 + choff + o;
    xh[d] = h;
    xl[d] = f2bf(y - bf2f(h));
}

// ---------------------------------------------------------------------------
// Final BN stats over y5 (PP x 512)
__global__ __launch_bounds__(256) void final_stats(const float* __restrict__ y5,
                                                   float* __restrict__ partial) {
    int blk = blockIdx.x, t = threadIdx.x;
    float s1a = 0.f, s2a = 0.f, s1b = 0.f, s2b = 0.f;
    for (int rr = 0; rr < 128; ++rr) {
        size_t row = (size_t)(blk * 128 + rr) * 512;
        float va = y5[row + t], vb = y5[row + t + 256];
        s1a += va; s2a = fmaf(va, va, s2a);
        s1b += vb; s2b = fmaf(vb, vb, s2b);
    }
    partial[((size_t)blk * 512 + t) * 2 + 0] = s1a;
    partial[((size_t)blk * 512 + t) * 2 + 1] = s2a;
    partial[((size_t)blk * 512 + t + 256) * 2 + 0] = s1b;
    partial[((size_t)blk * 512 + t + 256) * 2 + 1] = s2b;
}

// grid = 512 blocks, 64 threads: one channel per block
__global__ __launch_bounds__(64) void final_reduce(const float* __restrict__ partial, int nblk,
                                                   float cnt,
                                                   const float* __restrict__ g,
                                                   const float* __restrict__ bsh,
                                                   float* __restrict__ st) {
    int c = blockIdx.x, tid = threadIdx.x;
    float s1 = 0.f, s2 = 0.f;
    for (int bk = tid; bk < nblk; bk += 64) {
        size_t base = ((size_t)bk * 512 + c) * 2;
        s1 += partial[base];
        s2 += partial[base + 1];
    }
    #pragma unroll
    for (int s = 32; s > 0; s >>= 1) {
        s1 += __shfl_down(s1, s, 64);
        s2 += __shfl_down(s2, s, 64);
    }
    if (tid == 0) {
        float mu = s1 / cnt;
        float var = s2 / cnt - mu * mu;
        float x = var + EPSB;
        float rr = rsqrtf(x);
        rr = rr * (1.5f - 0.5f * x * rr * rr);
        float sc = g[c] * rr;
        st[c] = sc;
        st[512 + c] = bsh[c] - mu * sc;
    }
}

// affine+lrelu + transpose (B,N,512) -> (B,512,N)
__global__ __launch_bounds__(256) void final_apply(const float* __restrict__ y5,
                                                   const float* __restrict__ st,
                                                   float* __restrict__ out) {
    __shared__ float tile[32][33];
    int n0 = blockIdx.x * 32, o0 = blockIdx.y * 32, b = blockIdx.z;
    int tx = threadIdx.x, ty = threadIdx.y;
    for (int i = 0; i < 4; ++i) {
        int nl = ty + i * 8;
        tile[nl][tx] = y5[((size_t)(b * NN + n0 + nl)) * 512 + o0 + tx];
    }
    __syncthreads();
    for (int i = 0; i < 4; ++i) {
        int ol = ty + i * 8;
        int o = o0 + ol;
        float sc = st[o], tt = st[512 + o];
        float yv = fmaf(sc, tile[tx][ol], tt);
        yv = (yv >= 0.f) ? yv : LEAK * yv;
        out[((size_t)b * 512 + o) * NN + n0 + tx] = yv;
    }
}

// ---------------------------------------------------------------------------
extern "C" void kernel_launch(void* const* d_in, const int* in_sizes, int n_in,
                              void* d_out, int out_size, void* d_ws, size_t ws_size,
                              hipStream_t stream) {
    const float* pts = (const float*)d_in[0];
    const float* w[5]; const float* g[5]; const float* bsh[5];
    for (int i = 0; i < 5; ++i) {
        w[i]   = (const float*)d_in[1 + 3 * i];
        g[i]   = (const float*)d_in[2 + 3 * i];
        bsh[i] = (const float*)d_in[3 + 3 * i];
    }
    float* out = (float*)d_out;

    // workspace layout (floats unless noted)
    unsigned short* xh = (unsigned short*)d_ws;              // PP*512 bf16 hi
    unsigned short* xl = xh + (size_t)PP * 512;              // PP*512 bf16 lo
    float* u    = (float*)(xl + (size_t)PP * 512);           // PP*256
    float* v    = u    + (size_t)PP * 256;                   // PP*256
    float* mxb  = v    + (size_t)PP * 256;                   // PP*256
    float* mnb  = mxb  + (size_t)PP * 256;                   // PP*256
    float* y5   = u;                                         // overlay u+v (PP*512)
    float* ptst = mnb  + (size_t)PP * 256;                   // PP*2
    int*   idxb = (int*)(ptst + (size_t)PP * 2);             // PP*20
    float* part = (float*)(idxb + (size_t)PP * KK);          // 512*256*2 floats (1MB)
    float* st   = part + (size_t)512 * 256 * 2;              // 1024
    unsigned short* bmh = (unsigned short*)part;             // overlay part
    unsigned short* bml = bmh + (size_t)512 * 512;

    transpose_pts<<<(PP + 255) / 256, 256, 0, stream>>>(pts, ptst);
    knn_kernel<<<PP, 256, 0, stream>>>(pts, idxb);

    const int Cs[4]    = {2, 64, 64, 128};
    const int Os[4]    = {64, 64, 128, 256};
    const int choffs[4]= {0, 64, 128, 256};
    const int inoffs[4]= {0, 0, 64, 128};

    for (int li = 0; li < 4; ++li) {
        int C = Cs[li], O = Os[li];
        if (li == 0) {
            dim3 gg(PP / 64, (2 * O) / 64);
            proj_gemm<<<gg, 256, 0, stream>>>(ptst, 2, C, w[li], O, 0, u, v);
        } else {
            int total = 2 * O * C;
            convert_w<<<(total + 255) / 256, 256, 0, stream>>>(w[li], O, C, 0, bmh, bml);
            dim3 gg(PP / 128, (2 * O) / 128);
            mfma_gemm<<<gg, 256, 0, stream>>>(xh + inoffs[li], xl + inoffs[li], 512, C,
                                              bmh, bml, O, 0, u, v);
        }
        edge_stats<<<PP / 16, 256, 0, stream>>>(u, v, idxb, O, mxb, mnb, part);
        stats_reduce<<<O, 256, 0, stream>>>(part, PP / 16, O, (float)((size_t)PP * KK),
                                            g[li], bsh[li], st);
        apply_edge<<<(PP * O + 255) / 256, 256, 0, stream>>>(mxb, mnb, st, O, choffs[li], xh, xl);
    }

    // final conv1d 512->512 (split-bf16 MFMA) + BN + lrelu, transposed output
    convert_w<<<(512 * 512 + 255) / 256, 256, 0, stream>>>(w[4], 512, 512, 1, bmh, bml);
    dim3 gf(PP / 128, 512 / 128);
    mfma_gemm<<<gf, 256, 0, stream>>>(xh, xl, 512, 512, bmh, bml, 512, 1, y5, nullptr);
    final_stats<<<64, 256, 0, stream>>>(y5, part);
    final_reduce<<<512, 64, 0, stream>>>(part, 64, (float)PP, g[4], bsh[4], st);
    final_apply<<<dim3(NN / 32, 512 / 32, BB), dim3(32, 8), 0, stream>>>(y5, st, out);
}

// Round 6
// 229.215 us; speedup vs baseline: 4.9439x; 1.2715x over previous
//
#include <hip/hip_runtime.h>
#include <hip/hip_bf16.h>
#include <math.h>

// Problem constants
#define BB 2
#define NN 4096
#define PP (BB*NN)      // 8192 points total
#define KK 20
#define LEAK 0.2f
#define EPSB 1e-5f

typedef short sv8 __attribute__((ext_vector_type(8)));   // 8 bf16 (4 VGPRs)
typedef float f4  __attribute__((ext_vector_type(4)));   // 4 fp32 acc

__device__ inline unsigned short f2bf(float f) {         // RNE fp32->bf16
    unsigned u = __float_as_uint(f);
    unsigned r = (u + 0x7FFFu + ((u >> 16) & 1u)) >> 16;
    return (unsigned short)r;
}
__device__ inline float bf2f(unsigned short h) {
    return __uint_as_float((unsigned)h << 16);
}
__device__ inline void gload16(const void* g, void* l) {
    __builtin_amdgcn_global_load_lds(
        (const __attribute__((address_space(1))) unsigned int*)g,
        (__attribute__((address_space(3))) unsigned int*)l, 16, 0, 0);
}

// ---------------------------------------------------------------------------
// transpose pts (B,2,N) -> (B,N,2)
__global__ void transpose_pts(const float* __restrict__ pts, float* __restrict__ pts_t) {
    int e = blockIdx.x * 256 + threadIdx.x;
    if (e >= PP) return;
    int b = e / NN, n = e % NN;
    pts_t[(size_t)e * 2 + 0] = pts[(size_t)b * 2 * NN + n];
    pts_t[(size_t)e * 2 + 1] = pts[(size_t)b * 2 * NN + NN + n];
}

// ---------------------------------------------------------------------------
// kNN v4: histogram radix-select (verified R5).
__global__ __launch_bounds__(256) void knn_kernel(const float* __restrict__ pts,
                                                  int* __restrict__ idx) {
    __shared__ unsigned int hist[256];
    __shared__ unsigned int scanres[3];
    __shared__ unsigned int cnt2[2];
    __shared__ unsigned long long blist[512];

    int r = blockIdx.x;            // b*N + n
    int b = r >> 12, n = r & (NN - 1);
    const float* X0 = pts + (size_t)b * 2 * NN;
    const float* X1 = X0 + NN;
    int tid = threadIdx.x;
    float x0n = X0[n], x1n = X1[n];
    float xxn = __fadd_rn(__fmul_rn(x0n, x0n), __fmul_rn(x1n, x1n));
    float negxxn = __fsub_rn(0.f, xxn);

    float pdv[16];
    #pragma unroll
    for (int q = 0; q < 16; ++q) {
        int m = q * 256 + tid;
        float x0m = X0[m], x1m = X1[m];
        float xxm = __fadd_rn(__fmul_rn(x0m, x0m), __fmul_rn(x1m, x1m));
        float dot = __builtin_fmaf(x1n, x1m, __fmul_rn(x0n, x0m));
        float inner = __fmul_rn(-2.f, dot);
        float t1 = __fsub_rn(negxxn, inner);
        pdv[q] = __fsub_rn(t1, xxm);
    }

    int shift = 24;
    for (int attempt = 0; attempt < 3; ++attempt) {
        hist[tid] = 0;
        __syncthreads();
        float scale = (float)(1u << shift);
        #pragma unroll
        for (int q = 0; q < 16; ++q) {
            float s = fmaxf(-pdv[q], 0.f);
            unsigned int ki = (unsigned int)fminf(s * scale, 4.294e9f);
            unsigned int bin = ki >> 16;
            if (bin < 255u) atomicAdd(&hist[bin], 1u);
        }
        __syncthreads();
        if (tid < 64) {
            uint4 hv = *(const uint4*)&hist[tid * 4];
            unsigned int p0 = hv.x, p1 = p0 + hv.y, p2 = p1 + hv.z, p3 = p2 + hv.w;
            unsigned int lanesum = p3, inc = p3;
            #pragma unroll
            for (int s2 = 1; s2 < 64; s2 <<= 1) {
                unsigned int o = __shfl_up(inc, s2, 64);
                if (tid >= s2) inc += o;
            }
            unsigned int excl = inc - lanesum;
            bool flag = (inc >= KK);
            unsigned long long bal = __ballot(flag);
            int firstlane = (bal == 0ULL) ? -1 : (__ffsll((long long)bal) - 1);
            if (tid == 0) scanres[0] = (bal != 0ULL) ? 1u : 0u;
            if (tid == firstlane) {
                unsigned int c0 = excl + p0, c1 = excl + p1, c2 = excl + p2;
                int t = (c0 >= KK) ? 0 : (c1 >= KK) ? 1 : (c2 >= KK) ? 2 : 3;
                unsigned int cumb = (t == 0) ? excl : (t == 1) ? c0 : (t == 2) ? c1 : c2;
                scanres[1] = (unsigned)(tid * 4 + t);
                scanres[2] = cumb;
            }
        }
        __syncthreads();
        if (scanres[0]) break;
        shift -= 6;
        __syncthreads();
    }

    unsigned int bstar = scanres[1];
    unsigned int cumb  = scanres[2];
    if (tid == 0) { cnt2[0] = 0; cnt2[1] = 0; }
    __syncthreads();

    float scale = (float)(1u << shift);
    #pragma unroll
    for (int q = 0; q < 16; ++q) {
        float s = fmaxf(-pdv[q], 0.f);
        unsigned int ki = (unsigned int)fminf(s * scale, 4.294e9f);
        unsigned int bin = ki >> 16;
        if (bin > 255u) bin = 255u;
        int m = q * 256 + tid;
        if (bin < bstar) {
            unsigned int slot = atomicAdd(&cnt2[0], 1u);
            idx[(size_t)r * KK + slot] = m;
        } else if (bin == bstar) {
            unsigned int pos = atomicAdd(&cnt2[1], 1u);
            if (pos < 512u) {
                unsigned int ub = __float_as_uint(pdv[q]);
                unsigned int fk = (ub & 0x80000000u) ? ~ub : (ub | 0x80000000u);
                blist[pos] = ((unsigned long long)(~fk) << 32) | (unsigned int)m;
            }
        }
    }
    __syncthreads();

    int need = KK - (int)cumb;
    int L = (int)min(cnt2[1], 512u);
    if (tid < 64) {
        unsigned long long e[8];
        #pragma unroll
        for (int i = 0; i < 8; ++i) {
            int p = tid + 64 * i;
            e[i] = (p < L) ? blist[p] : ~0ULL;
        }
        unsigned long long lmin = e[0];
        #pragma unroll
        for (int i = 1; i < 8; ++i) lmin = (e[i] < lmin) ? e[i] : lmin;
        for (int p = 0; p < need; ++p) {
            unsigned long long gm = lmin;
            #pragma unroll
            for (int s2 = 32; s2 > 0; s2 >>= 1) {
                unsigned long long o = __shfl_xor(gm, s2, 64);
                if (o < gm) gm = o;
            }
            if (lmin == gm) {
                #pragma unroll
                for (int i = 0; i < 8; ++i) if (e[i] == gm) e[i] = ~0ULL;
                lmin = e[0];
                #pragma unroll
                for (int i = 1; i < 8; ++i) lmin = (e[i] < lmin) ? e[i] : lmin;
                idx[(size_t)r * KK + cumb + p] = (int)(gm & 0xFFFFFFFFu);
            }
        }
    }
}

// ---------------------------------------------------------------------------
// fp32 projection GEMM (layer 1 only: K=2).
__global__ __launch_bounds__(256) void proj_gemm(const float* __restrict__ X, int ldx, int C,
                                                 const float* __restrict__ W, int O, int mode,
                                                 float* __restrict__ outU, float* __restrict__ outV) {
    __shared__ float Xs[16][65];
    __shared__ float Ws[16][65];
    int row0 = blockIdx.x * 64, col0 = blockIdx.y * 64;
    int tid = threadIdx.x;
    int tx = tid % 16, ty = tid / 16;
    float acc[4][4] = {};
    for (int c0 = 0; c0 < C; c0 += 16) {
        for (int i = 0; i < 4; ++i) {
            int mm = ty + i * 16;
            float val = 0.f;
            if (c0 + tx < C) val = X[(size_t)(row0 + mm) * ldx + c0 + tx];
            Xs[tx][mm] = val;
        }
        for (int i = 0; i < 4; ++i) {
            int jj = ty + i * 16;
            int j = col0 + jj;
            float val = 0.f;
            if (c0 + tx < C) {
                if (mode == 0) {
                    if (j < O) val = W[(size_t)j * (2 * C) + c0 + tx];
                    else {
                        const float* wr = W + (size_t)(j - O) * (2 * C);
                        val = wr[C + c0 + tx] - wr[c0 + tx];
                    }
                } else {
                    val = W[(size_t)j * C + c0 + tx];
                }
            }
            Ws[tx][jj] = val;
        }
        __syncthreads();
        int kmax = (C - c0 < 16) ? (C - c0) : 16;
        for (int kk = 0; kk < kmax; ++kk) {
            float a[4], bw[4];
            #pragma unroll
            for (int i = 0; i < 4; ++i) a[i] = Xs[kk][ty * 4 + i];
            #pragma unroll
            for (int j = 0; j < 4; ++j) bw[j] = Ws[kk][tx * 4 + j];
            #pragma unroll
            for (int i = 0; i < 4; ++i)
                #pragma unroll
                for (int j = 0; j < 4; ++j)
                    acc[i][j] = fmaf(a[i], bw[j], acc[i][j]);
        }
        __syncthreads();
    }
    for (int i = 0; i < 4; ++i) {
        int rr = row0 + ty * 4 + i;
        for (int j = 0; j < 4; ++j) {
            int jg = col0 + tx * 4 + j;
            float vv = acc[i][j];
            if (mode == 0) {
                if (jg < O) outU[(size_t)rr * O + jg] = vv;
                else        outV[(size_t)rr * O + (jg - O)] = vv;
            } else {
                outU[(size_t)rr * O + jg] = vv;
            }
        }
    }
}

// ---------------------------------------------------------------------------
// Weight conversion: build Bmat rows and split into hi/lo bf16 planes.
__global__ void convert_w(const float* __restrict__ w, int O, int C, int mode,
                          unsigned short* __restrict__ bh, unsigned short* __restrict__ bl) {
    int total = (mode == 0 ? 2 * O : O) * C;
    int i = blockIdx.x * 256 + threadIdx.x;
    if (i >= total) return;
    int j = i / C, c = i - j * C;
    float v;
    if (mode == 0) {
        if (j < O) v = w[(size_t)j * 2 * C + c];
        else {
            const float* wr = w + (size_t)(j - O) * 2 * C;
            v = wr[C + c] - wr[c];
        }
    } else {
        v = w[(size_t)j * C + c];
    }
    unsigned short h = f2bf(v);
    bh[i] = h;
    bl[i] = f2bf(v - bf2f(h));
}

// ---------------------------------------------------------------------------
// Split-bf16 MFMA GEMM (verified R4/R5).
__global__ __launch_bounds__(256) void mfma_gemm(const unsigned short* __restrict__ Xh,
                                                 const unsigned short* __restrict__ Xl, int ldx,
                                                 int K,
                                                 const unsigned short* __restrict__ Bh,
                                                 const unsigned short* __restrict__ Bl,
                                                 int O, int mode,
                                                 float* __restrict__ outU,
                                                 float* __restrict__ outV) {
    __shared__ unsigned short Ah[512 * 8], Al[512 * 8], Bhs[512 * 8], Bls[512 * 8];
    int row0 = blockIdx.x * 128, col0 = blockIdx.y * 128;
    int tid = threadIdx.x;
    int wid = tid >> 6, lane = tid & 63;
    int wm = wid & 1, wn = wid >> 1;
    int l15 = lane & 15, l4 = lane >> 4;

    f4 acc[4][4];
    #pragma unroll
    for (int i = 0; i < 4; ++i)
        #pragma unroll
        for (int j = 0; j < 4; ++j) { acc[i][j][0]=0.f; acc[i][j][1]=0.f; acc[i][j][2]=0.f; acc[i][j][3]=0.f; }

    for (int k0 = 0; k0 < K; k0 += 32) {
        #pragma unroll
        for (int j = 0; j < 2; ++j) {
            int c = tid + 256 * j;
            int m = c & 127, kb = c >> 7;
            size_t ga = (size_t)(row0 + m) * ldx + k0 + kb * 8;
            size_t gb = (size_t)(col0 + m) * K + k0 + kb * 8;
            gload16(Xh + ga, &Ah[(size_t)(wid * 64 + 256 * j) * 8]);
            gload16(Xl + ga, &Al[(size_t)(wid * 64 + 256 * j) * 8]);
            gload16(Bh + gb, &Bhs[(size_t)(wid * 64 + 256 * j) * 8]);
            gload16(Bl + gb, &Bls[(size_t)(wid * 64 + 256 * j) * 8]);
        }
        __syncthreads();

        sv8 bhf[4], blf[4];
        #pragma unroll
        for (int fn = 0; fn < 4; ++fn) {
            int nn2 = wn * 64 + fn * 16 + l15;
            bhf[fn] = *(const sv8*)&Bhs[(size_t)(l4 * 128 + nn2) * 8];
            blf[fn] = *(const sv8*)&Bls[(size_t)(l4 * 128 + nn2) * 8];
        }
        #pragma unroll
        for (int fm = 0; fm < 4; ++fm) {
            int m = wm * 64 + fm * 16 + l15;
            sv8 ah = *(const sv8*)&Ah[(size_t)(l4 * 128 + m) * 8];
            sv8 al = *(const sv8*)&Al[(size_t)(l4 * 128 + m) * 8];
            #pragma unroll
            for (int fn = 0; fn < 4; ++fn) {
                acc[fm][fn] = __builtin_amdgcn_mfma_f32_16x16x32_bf16(ah, bhf[fn], acc[fm][fn], 0, 0, 0);
                acc[fm][fn] = __builtin_amdgcn_mfma_f32_16x16x32_bf16(ah, blf[fn], acc[fm][fn], 0, 0, 0);
                acc[fm][fn] = __builtin_amdgcn_mfma_f32_16x16x32_bf16(al, bhf[fn], acc[fm][fn], 0, 0, 0);
            }
        }
        __syncthreads();
    }

    #pragma unroll
    for (int fm = 0; fm < 4; ++fm) {
        int rbase = row0 + wm * 64 + fm * 16 + l4 * 4;
        #pragma unroll
        for (int fn = 0; fn < 4; ++fn) {
            int jg = col0 + wn * 64 + fn * 16 + l15;
            #pragma unroll
            for (int e = 0; e < 4; ++e) {
                float vv = acc[fm][fn][e];
                int p = rbase + e;
                if (mode == 1 || jg < O) outU[(size_t)p * O + jg] = vv;
                else                     outV[(size_t)p * O + (jg - O)] = vv;
            }
        }
    }
}

// ---------------------------------------------------------------------------
// edge_stats v2: float2 channel pairs, full-unroll prefetch of all 20 rows,
// PS = 512/O point-slots per block, PPL points per thread, LDS-reduced
// per-block channel sums -> partial[blk][2*O] (s1[O], s2[O]).
__global__ __launch_bounds__(256) void edge_stats(const float* __restrict__ u,
                                                  const float* __restrict__ v,
                                                  const int* __restrict__ idx,
                                                  int O, int PPL,
                                                  float* __restrict__ mx, float* __restrict__ mn,
                                                  float* __restrict__ partial) {
    __shared__ float red[4 * 256];
    int tid = threadIdx.x;
    int CH2 = O >> 1;
    int PS = 256 / CH2;
    int co = tid % CH2;
    int ps = tid / CH2;
    float s1a = 0.f, s1b = 0.f, s2a = 0.f, s2b = 0.f;
    for (int pi = 0; pi < PPL; ++pi) {
        int r = (blockIdx.x * PS + ps) * PPL + pi;
        int b = r >> 12;
        const float* ub = u + (size_t)b * NN * O + 2 * co;
        float2 vv = *(const float2*)&v[(size_t)r * O + 2 * co];
        const int* ip = idx + (size_t)r * KK;
        int mreg[KK];
        #pragma unroll
        for (int k = 0; k < KK; ++k) mreg[k] = ip[k];
        float2 uv[KK];
        #pragma unroll
        for (int k = 0; k < KK; ++k) uv[k] = *(const float2*)&ub[(size_t)mreg[k] * O];
        float bxa = -INFINITY, bxb = -INFINITY, bna = INFINITY, bnb = INFINITY;
        #pragma unroll
        for (int k = 0; k < KK; ++k) {
            float y0 = uv[k].x + vv.x, y1 = uv[k].y + vv.y;
            s1a += y0; s2a = fmaf(y0, y0, s2a);
            s1b += y1; s2b = fmaf(y1, y1, s2b);
            bxa = fmaxf(bxa, y0); bna = fminf(bna, y0);
            bxb = fmaxf(bxb, y1); bnb = fminf(bnb, y1);
        }
        *(float2*)&mx[(size_t)r * O + 2 * co] = make_float2(bxa, bxb);
        *(float2*)&mn[(size_t)r * O + 2 * co] = make_float2(bna, bnb);
    }
    red[0 * 256 + tid] = s1a;
    red[1 * 256 + tid] = s1b;
    red[2 * 256 + tid] = s2a;
    red[3 * 256 + tid] = s2b;
    __syncthreads();
    for (int s = PS >> 1; s > 0; s >>= 1) {
        if (ps < s) {
            int oth = tid + s * CH2;
            red[0 * 256 + tid] += red[0 * 256 + oth];
            red[1 * 256 + tid] += red[1 * 256 + oth];
            red[2 * 256 + tid] += red[2 * 256 + oth];
            red[3 * 256 + tid] += red[3 * 256 + oth];
        }
        __syncthreads();
    }
    if (ps == 0) {
        size_t base = (size_t)blockIdx.x * 2 * O;
        partial[base + 2 * co]         = red[0 * 256 + tid];
        partial[base + 2 * co + 1]     = red[1 * 256 + tid];
        partial[base + O + 2 * co]     = red[2 * 256 + tid];
        partial[base + O + 2 * co + 1] = red[3 * 256 + tid];
    }
}

// reduce partial[blk][2*O] -> per-channel scale/shift.  grid = O blocks.
__global__ __launch_bounds__(256) void stats_reduce(const float* __restrict__ partial, int nblk,
                                                    int O, float cnt,
                                                    const float* __restrict__ g,
                                                    const float* __restrict__ bsh,
                                                    float* __restrict__ st) {
    __shared__ float r1[4], r2[4];
    int o = blockIdx.x, tid = threadIdx.x;
    float s1 = 0.f, s2 = 0.f;
    for (int bk = tid; bk < nblk; bk += 256) {
        size_t base = (size_t)bk * 2 * O;
        s1 += partial[base + o];
        s2 += partial[base + O + o];
    }
    #pragma unroll
    for (int s = 32; s > 0; s >>= 1) {
        s1 += __shfl_down(s1, s, 64);
        s2 += __shfl_down(s2, s, 64);
    }
    if ((tid & 63) == 0) { r1[tid >> 6] = s1; r2[tid >> 6] = s2; }
    __syncthreads();
    if (tid == 0) {
        s1 = r1[0] + r1[1] + r1[2] + r1[3];
        s2 = r2[0] + r2[1] + r2[2] + r2[3];
        float mu = s1 / cnt;
        float var = s2 / cnt - mu * mu;
        float x = var + EPSB;
        float rr = rsqrtf(x);
        rr = rr * (1.5f - 0.5f * x * rr * rr);
        float sc = g[o] * rr;
        st[o] = sc;
        st[O + o] = bsh[o] - mu * sc;
    }
}

// select max/min by scale sign, affine + LeakyReLU, write hi/lo bf16 planes
__global__ void apply_edge(const float* __restrict__ mx, const float* __restrict__ mn,
                           const float* __restrict__ st, int O, int choff,
                           unsigned short* __restrict__ xh, unsigned short* __restrict__ xl) {
    int e = blockIdx.x * 256 + threadIdx.x;
    if (e >= PP * O) return;
    int r = e / O, o = e % O;
    float sc = st[o], tt = st[O + o];
    float base = (sc >= 0.f) ? mx[e] : mn[e];
    float y = fmaf(sc, base, tt);
    y = (y >= 0.f) ? y : LEAK * y;
    unsigned short h = f2bf(y);
    size_t d = (size_t)r * 512 + choff + o;
    xh[d] = h;
    xl[d] = f2bf(y - bf2f(h));
}

// ---------------------------------------------------------------------------
// Final BN stats over y5 (PP x 512)
__global__ __launch_bounds__(256) void final_stats(const float* __restrict__ y5,
                                                   float* __restrict__ partial) {
    int blk = blockIdx.x, t = threadIdx.x;
    float s1a = 0.f, s2a = 0.f, s1b = 0.f, s2b = 0.f;
    for (int rr = 0; rr < 128; ++rr) {
        size_t row = (size_t)(blk * 128 + rr) * 512;
        float va = y5[row + t], vb = y5[row + t + 256];
        s1a += va; s2a = fmaf(va, va, s2a);
        s1b += vb; s2b = fmaf(vb, vb, s2b);
    }
    partial[((size_t)blk * 512 + t) * 2 + 0] = s1a;
    partial[((size_t)blk * 512 + t) * 2 + 1] = s2a;
    partial[((size_t)blk * 512 + t + 256) * 2 + 0] = s1b;
    partial[((size_t)blk * 512 + t + 256) * 2 + 1] = s2b;
}

// grid = 512 blocks, 64 threads: one channel per block
__global__ __launch_bounds__(64) void final_reduce(const float* __restrict__ partial, int nblk,
                                                   float cnt,
                                                   const float* __restrict__ g,
                                                   const float* __restrict__ bsh,
                                                   float* __restrict__ st) {
    int c = blockIdx.x, tid = threadIdx.x;
    float s1 = 0.f, s2 = 0.f;
    for (int bk = tid; bk < nblk; bk += 64) {
        size_t base = ((size_t)bk * 512 + c) * 2;
        s1 += partial[base];
        s2 += partial[base + 1];
    }
    #pragma unroll
    for (int s = 32; s > 0; s >>= 1) {
        s1 += __shfl_down(s1, s, 64);
        s2 += __shfl_down(s2, s, 64);
    }
    if (tid == 0) {
        float mu = s1 / cnt;
        float var = s2 / cnt - mu * mu;
        float x = var + EPSB;
        float rr = rsqrtf(x);
        rr = rr * (1.5f - 0.5f * x * rr * rr);
        float sc = g[c] * rr;
        st[c] = sc;
        st[512 + c] = bsh[c] - mu * sc;
    }
}

// affine+lrelu + transpose (B,N,512) -> (B,512,N)
__global__ __launch_bounds__(256) void final_apply(const float* __restrict__ y5,
                                                   const float* __restrict__ st,
                                                   float* __restrict__ out) {
    __shared__ float tile[32][33];
    int n0 = blockIdx.x * 32, o0 = blockIdx.y * 32, b = blockIdx.z;
    int tx = threadIdx.x, ty = threadIdx.y;
    for (int i = 0; i < 4; ++i) {
        int nl = ty + i * 8;
        tile[nl][tx] = y5[((size_t)(b * NN + n0 + nl)) * 512 + o0 + tx];
    }
    __syncthreads();
    for (int i = 0; i < 4; ++i) {
        int ol = ty + i * 8;
        int o = o0 + ol;
        float sc = st[o], tt = st[512 + o];
        float yv = fmaf(sc, tile[tx][ol], tt);
        yv = (yv >= 0.f) ? yv : LEAK * yv;
        out[((size_t)b * 512 + o) * NN + n0 + tx] = yv;
    }
}

// ---------------------------------------------------------------------------
extern "C" void kernel_launch(void* const* d_in, const int* in_sizes, int n_in,
                              void* d_out, int out_size, void* d_ws, size_t ws_size,
                              hipStream_t stream) {
    const float* pts = (const float*)d_in[0];
    const float* w[5]; const float* g[5]; const float* bsh[5];
    for (int i = 0; i < 5; ++i) {
        w[i]   = (const float*)d_in[1 + 3 * i];
        g[i]   = (const float*)d_in[2 + 3 * i];
        bsh[i] = (const float*)d_in[3 + 3 * i];
    }
    float* out = (float*)d_out;

    // workspace layout (floats unless noted)
    unsigned short* xh = (unsigned short*)d_ws;              // PP*512 bf16 hi
    unsigned short* xl = xh + (size_t)PP * 512;              // PP*512 bf16 lo
    float* u    = (float*)(xl + (size_t)PP * 512);           // PP*256
    float* v    = u    + (size_t)PP * 256;                   // PP*256
    float* mxb  = v    + (size_t)PP * 256;                   // PP*256
    float* mnb  = mxb  + (size_t)PP * 256;                   // PP*256
    float* y5   = u;                                         // overlay u+v (PP*512)
    float* ptst = mnb  + (size_t)PP * 256;                   // PP*2
    int*   idxb = (int*)(ptst + (size_t)PP * 2);             // PP*20
    float* part = (float*)(idxb + (size_t)PP * KK);          // up to 4 MB (1M floats)
    float* st   = part + (size_t)1048576;                    // 1024
    unsigned short* bmh = (unsigned short*)part;             // overlay part
    unsigned short* bml = bmh + (size_t)512 * 512;

    transpose_pts<<<(PP + 255) / 256, 256, 0, stream>>>(pts, ptst);
    knn_kernel<<<PP, 256, 0, stream>>>(pts, idxb);

    const int Cs[4]    = {2, 64, 64, 128};
    const int Os[4]    = {64, 64, 128, 256};
    const int choffs[4]= {0, 64, 128, 256};
    const int inoffs[4]= {0, 0, 64, 128};

    for (int li = 0; li < 4; ++li) {
        int C = Cs[li], O = Os[li];
        if (li == 0) {
            dim3 gg(PP / 64, (2 * O) / 64);
            proj_gemm<<<gg, 256, 0, stream>>>(ptst, 2, C, w[li], O, 0, u, v);
        } else {
            int total = 2 * O * C;
            convert_w<<<(total + 255) / 256, 256, 0, stream>>>(w[li], O, C, 0, bmh, bml);
            dim3 gg(PP / 128, (2 * O) / 128);
            mfma_gemm<<<gg, 256, 0, stream>>>(xh + inoffs[li], xl + inoffs[li], 512, C,
                                              bmh, bml, O, 0, u, v);
        }
        int PS  = 512 / O;                       // point slots per block
        int PPL = (O == 256) ? 2 : 1;            // points per thread
        int nblk = PP / (PS * PPL);              // 1024 / 2048 / 2048
        edge_stats<<<nblk, 256, 0, stream>>>(u, v, idxb, O, PPL, mxb, mnb, part);
        stats_reduce<<<O, 256, 0, stream>>>(part, nblk, O, (float)((size_t)PP * KK),
                                            g[li], bsh[li], st);
        apply_edge<<<(PP * O + 255) / 256, 256, 0, stream>>>(mxb, mnb, st, O, choffs[li], xh, xl);
    }

    // final conv1d 512->512 (split-bf16 MFMA) + BN + lrelu, transposed output
    convert_w<<<(512 * 512 + 255) / 256, 256, 0, stream>>>(w[4], 512, 512, 1, bmh, bml);
    dim3 gf(PP / 128, 512 / 128);
    mfma_gemm<<<gf, 256, 0, stream>>>(xh, xl, 512, 512, bmh, bml, 512, 1, y5, nullptr);
    final_stats<<<64, 256, 0, stream>>>(y5, part);
    final_reduce<<<512, 64, 0, stream>>>(part, 64, (float)PP, g[4], bsh[4], st);
    final_apply<<<dim3(NN / 32, 512 / 32, BB), dim3(32, 8), 0, stream>>>(y5, st, out);
}

// Round 7
// 194.010 us; speedup vs baseline: 5.8410x; 1.1815x over previous
//
#include <hip/hip_runtime.h>
#include <hip/hip_bf16.h>
#include <math.h>

// Problem constants
#define BB 2
#define NN 4096
#define PP (BB*NN)      // 8192 points total
#define KK 20
#define LEAK 0.2f
#define EPSB 1e-5f

typedef short sv8 __attribute__((ext_vector_type(8)));   // 8 bf16 (4 VGPRs)
typedef float f4  __attribute__((ext_vector_type(4)));   // 4 fp32 acc

__device__ inline unsigned short f2bf(float f) {         // RNE fp32->bf16
    unsigned u = __float_as_uint(f);
    unsigned r = (u + 0x7FFFu + ((u >> 16) & 1u)) >> 16;
    return (unsigned short)r;
}
__device__ inline float bf2f(unsigned short h) {
    return __uint_as_float((unsigned)h << 16);
}
__device__ inline void gload16(const void* g, void* l) {
    __builtin_amdgcn_global_load_lds(
        (const __attribute__((address_space(1))) unsigned int*)g,
        (__attribute__((address_space(3))) unsigned int*)l, 16, 0, 0);
}

// ---------------------------------------------------------------------------
// kNN v4: histogram radix-select (verified R5/R6). Also emits pts_t (B,N,2).
__global__ __launch_bounds__(256) void knn_kernel(const float* __restrict__ pts,
                                                  int* __restrict__ idx,
                                                  float* __restrict__ pts_t) {
    __shared__ unsigned int hist[256];
    __shared__ unsigned int scanres[3];
    __shared__ unsigned int cnt2[2];
    __shared__ unsigned long long blist[512];

    int r = blockIdx.x;            // b*N + n
    int b = r >> 12, n = r & (NN - 1);
    const float* X0 = pts + (size_t)b * 2 * NN;
    const float* X1 = X0 + NN;
    int tid = threadIdx.x;
    float x0n = X0[n], x1n = X1[n];
    if (tid == 0) {                // fold transpose_pts into knn
        pts_t[(size_t)r * 2 + 0] = x0n;
        pts_t[(size_t)r * 2 + 1] = x1n;
    }
    float xxn = __fadd_rn(__fmul_rn(x0n, x0n), __fmul_rn(x1n, x1n));
    float negxxn = __fsub_rn(0.f, xxn);

    float pdv[16];
    #pragma unroll
    for (int q = 0; q < 16; ++q) {
        int m = q * 256 + tid;
        float x0m = X0[m], x1m = X1[m];
        float xxm = __fadd_rn(__fmul_rn(x0m, x0m), __fmul_rn(x1m, x1m));
        float dot = __builtin_fmaf(x1n, x1m, __fmul_rn(x0n, x0m));
        float inner = __fmul_rn(-2.f, dot);
        float t1 = __fsub_rn(negxxn, inner);
        pdv[q] = __fsub_rn(t1, xxm);
    }

    int shift = 24;
    for (int attempt = 0; attempt < 3; ++attempt) {
        hist[tid] = 0;
        __syncthreads();
        float scale = (float)(1u << shift);
        #pragma unroll
        for (int q = 0; q < 16; ++q) {
            float s = fmaxf(-pdv[q], 0.f);
            unsigned int ki = (unsigned int)fminf(s * scale, 4.294e9f);
            unsigned int bin = ki >> 16;
            if (bin < 255u) atomicAdd(&hist[bin], 1u);
        }
        __syncthreads();
        if (tid < 64) {
            uint4 hv = *(const uint4*)&hist[tid * 4];
            unsigned int p0 = hv.x, p1 = p0 + hv.y, p2 = p1 + hv.z, p3 = p2 + hv.w;
            unsigned int lanesum = p3, inc = p3;
            #pragma unroll
            for (int s2 = 1; s2 < 64; s2 <<= 1) {
                unsigned int o = __shfl_up(inc, s2, 64);
                if (tid >= s2) inc += o;
            }
            unsigned int excl = inc - lanesum;
            bool flag = (inc >= KK);
            unsigned long long bal = __ballot(flag);
            int firstlane = (bal == 0ULL) ? -1 : (__ffsll((long long)bal) - 1);
            if (tid == 0) scanres[0] = (bal != 0ULL) ? 1u : 0u;
            if (tid == firstlane) {
                unsigned int c0 = excl + p0, c1 = excl + p1, c2 = excl + p2;
                int t = (c0 >= KK) ? 0 : (c1 >= KK) ? 1 : (c2 >= KK) ? 2 : 3;
                unsigned int cumb = (t == 0) ? excl : (t == 1) ? c0 : (t == 2) ? c1 : c2;
                scanres[1] = (unsigned)(tid * 4 + t);
                scanres[2] = cumb;
            }
        }
        __syncthreads();
        if (scanres[0]) break;
        shift -= 6;
        __syncthreads();
    }

    unsigned int bstar = scanres[1];
    unsigned int cumb  = scanres[2];
    if (tid == 0) { cnt2[0] = 0; cnt2[1] = 0; }
    __syncthreads();

    float scale = (float)(1u << shift);
    #pragma unroll
    for (int q = 0; q < 16; ++q) {
        float s = fmaxf(-pdv[q], 0.f);
        unsigned int ki = (unsigned int)fminf(s * scale, 4.294e9f);
        unsigned int bin = ki >> 16;
        if (bin > 255u) bin = 255u;
        int m = q * 256 + tid;
        if (bin < bstar) {
            unsigned int slot = atomicAdd(&cnt2[0], 1u);
            idx[(size_t)r * KK + slot] = m;
        } else if (bin == bstar) {
            unsigned int pos = atomicAdd(&cnt2[1], 1u);
            if (pos < 512u) {
                unsigned int ub = __float_as_uint(pdv[q]);
                unsigned int fk = (ub & 0x80000000u) ? ~ub : (ub | 0x80000000u);
                blist[pos] = ((unsigned long long)(~fk) << 32) | (unsigned int)m;
            }
        }
    }
    __syncthreads();

    int need = KK - (int)cumb;
    int L = (int)min(cnt2[1], 512u);
    if (tid < 64) {
        unsigned long long e[8];
        #pragma unroll
        for (int i = 0; i < 8; ++i) {
            int p = tid + 64 * i;
            e[i] = (p < L) ? blist[p] : ~0ULL;
        }
        unsigned long long lmin = e[0];
        #pragma unroll
        for (int i = 1; i < 8; ++i) lmin = (e[i] < lmin) ? e[i] : lmin;
        for (int p = 0; p < need; ++p) {
            unsigned long long gm = lmin;
            #pragma unroll
            for (int s2 = 32; s2 > 0; s2 >>= 1) {
                unsigned long long o = __shfl_xor(gm, s2, 64);
                if (o < gm) gm = o;
            }
            if (lmin == gm) {
                #pragma unroll
                for (int i = 0; i < 8; ++i) if (e[i] == gm) e[i] = ~0ULL;
                lmin = e[0];
                #pragma unroll
                for (int i = 1; i < 8; ++i) lmin = (e[i] < lmin) ? e[i] : lmin;
                idx[(size_t)r * KK + cumb + p] = (int)(gm & 0xFFFFFFFFu);
            }
        }
    }
}

// ---------------------------------------------------------------------------
// fp32 projection GEMM (layer 1 only: K=2).
__global__ __launch_bounds__(256) void proj_gemm(const float* __restrict__ X, int ldx, int C,
                                                 const float* __restrict__ W, int O, int mode,
                                                 float* __restrict__ outU, float* __restrict__ outV) {
    __shared__ float Xs[16][65];
    __shared__ float Ws[16][65];
    int row0 = blockIdx.x * 64, col0 = blockIdx.y * 64;
    int tid = threadIdx.x;
    int tx = tid % 16, ty = tid / 16;
    float acc[4][4] = {};
    for (int c0 = 0; c0 < C; c0 += 16) {
        for (int i = 0; i < 4; ++i) {
            int mm = ty + i * 16;
            float val = 0.f;
            if (c0 + tx < C) val = X[(size_t)(row0 + mm) * ldx + c0 + tx];
            Xs[tx][mm] = val;
        }
        for (int i = 0; i < 4; ++i) {
            int jj = ty + i * 16;
            int j = col0 + jj;
            float val = 0.f;
            if (c0 + tx < C) {
                if (mode == 0) {
                    if (j < O) val = W[(size_t)j * (2 * C) + c0 + tx];
                    else {
                        const float* wr = W + (size_t)(j - O) * (2 * C);
                        val = wr[C + c0 + tx] - wr[c0 + tx];
                    }
                } else {
                    val = W[(size_t)j * C + c0 + tx];
                }
            }
            Ws[tx][jj] = val;
        }
        __syncthreads();
        int kmax = (C - c0 < 16) ? (C - c0) : 16;
        for (int kk = 0; kk < kmax; ++kk) {
            float a[4], bw[4];
            #pragma unroll
            for (int i = 0; i < 4; ++i) a[i] = Xs[kk][ty * 4 + i];
            #pragma unroll
            for (int j = 0; j < 4; ++j) bw[j] = Ws[kk][tx * 4 + j];
            #pragma unroll
            for (int i = 0; i < 4; ++i)
                #pragma unroll
                for (int j = 0; j < 4; ++j)
                    acc[i][j] = fmaf(a[i], bw[j], acc[i][j]);
        }
        __syncthreads();
    }
    for (int i = 0; i < 4; ++i) {
        int rr = row0 + ty * 4 + i;
        for (int j = 0; j < 4; ++j) {
            int jg = col0 + tx * 4 + j;
            float vv = acc[i][j];
            if (mode == 0) {
                if (jg < O) outU[(size_t)rr * O + jg] = vv;
                else        outV[(size_t)rr * O + (jg - O)] = vv;
            } else {
                outU[(size_t)rr * O + jg] = vv;
            }
        }
    }
}

// ---------------------------------------------------------------------------
// One-shot weight conversion for layers 2..5 into persistent hi/lo planes.
// Layout: l2 [0,8192) O=64 C=64 m0 | l3 [8192,24576) O=128 C=64 m0 |
//         l4 [24576,90112) O=256 C=128 m0 | l5 [90112,352256) O=512 C=512 m1
__global__ __launch_bounds__(256) void convert_all(const float* __restrict__ w2,
                                                   const float* __restrict__ w3,
                                                   const float* __restrict__ w4,
                                                   const float* __restrict__ w5,
                                                   unsigned short* __restrict__ bh,
                                                   unsigned short* __restrict__ bl) {
    int i = blockIdx.x * 256 + threadIdx.x;
    if (i >= 352256) return;
    const float* w; int O, C, mode, base;
    if (i < 8192)       { w = w2; O = 64;  C = 64;  mode = 0; base = 0; }
    else if (i < 24576) { w = w3; O = 128; C = 64;  mode = 0; base = 8192; }
    else if (i < 90112) { w = w4; O = 256; C = 128; mode = 0; base = 24576; }
    else                { w = w5; O = 512; C = 512; mode = 1; base = 90112; }
    int j = i - base;
    int row = j / C, c = j - row * C;
    float v;
    if (mode == 0) {
        if (row < O) v = w[(size_t)row * 2 * C + c];
        else {
            const float* wr = w + (size_t)(row - O) * 2 * C;
            v = wr[C + c] - wr[c];
        }
    } else {
        v = w[(size_t)row * C + c];
    }
    unsigned short h = f2bf(v);
    bh[i] = h;
    bl[i] = f2bf(v - bf2f(h));
}

// ---------------------------------------------------------------------------
// Split-bf16 MFMA GEMM, 64x64 tile (4 waves 2x2, 32x32 wave tile, 16KB LDS).
// Same verified 2-barrier schedule / staging pattern as the 128-tile version.
// Always mode0 (UV split at O).
__global__ __launch_bounds__(256) void mfma_gemm64(const unsigned short* __restrict__ Xh,
                                                   const unsigned short* __restrict__ Xl,
                                                   int ldx, int K,
                                                   const unsigned short* __restrict__ Bh,
                                                   const unsigned short* __restrict__ Bl,
                                                   int O,
                                                   float* __restrict__ outU,
                                                   float* __restrict__ outV) {
    __shared__ unsigned short Ah[256 * 8], Al[256 * 8], Bhs[256 * 8], Bls[256 * 8];
    int row0 = blockIdx.x * 64, col0 = blockIdx.y * 64;
    int tid = threadIdx.x;
    int wid = tid >> 6, lane = tid & 63;
    int wm = wid & 1, wn = wid >> 1;
    int l15 = lane & 15, l4 = lane >> 4;
    int m = tid & 63, kb = tid >> 6;        // staging chunk -> (row, k-octet)

    f4 acc[2][2];
    #pragma unroll
    for (int i = 0; i < 2; ++i)
        #pragma unroll
        for (int j = 0; j < 2; ++j) { acc[i][j][0]=0.f; acc[i][j][1]=0.f; acc[i][j][2]=0.f; acc[i][j][3]=0.f; }

    for (int k0 = 0; k0 < K; k0 += 32) {
        size_t ga = (size_t)(row0 + m) * ldx + k0 + kb * 8;
        size_t gb = (size_t)(col0 + m) * K + k0 + kb * 8;
        gload16(Xh + ga, &Ah[(size_t)(wid * 64) * 8]);
        gload16(Xl + ga, &Al[(size_t)(wid * 64) * 8]);
        gload16(Bh + gb, &Bhs[(size_t)(wid * 64) * 8]);
        gload16(Bl + gb, &Bls[(size_t)(wid * 64) * 8]);
        __syncthreads();

        sv8 bhf[2], blf[2];
        #pragma unroll
        for (int fn = 0; fn < 2; ++fn) {
            int nn2 = wn * 32 + fn * 16 + l15;
            bhf[fn] = *(const sv8*)&Bhs[(size_t)(l4 * 64 + nn2) * 8];
            blf[fn] = *(const sv8*)&Bls[(size_t)(l4 * 64 + nn2) * 8];
        }
        #pragma unroll
        for (int fm = 0; fm < 2; ++fm) {
            int mm = wm * 32 + fm * 16 + l15;
            sv8 ah = *(const sv8*)&Ah[(size_t)(l4 * 64 + mm) * 8];
            sv8 al = *(const sv8*)&Al[(size_t)(l4 * 64 + mm) * 8];
            #pragma unroll
            for (int fn = 0; fn < 2; ++fn) {
                acc[fm][fn] = __builtin_amdgcn_mfma_f32_16x16x32_bf16(ah, bhf[fn], acc[fm][fn], 0, 0, 0);
                acc[fm][fn] = __builtin_amdgcn_mfma_f32_16x16x32_bf16(ah, blf[fn], acc[fm][fn], 0, 0, 0);
                acc[fm][fn] = __builtin_amdgcn_mfma_f32_16x16x32_bf16(al, bhf[fn], acc[fm][fn], 0, 0, 0);
            }
        }
        __syncthreads();
    }

    #pragma unroll
    for (int fm = 0; fm < 2; ++fm) {
        int rbase = row0 + wm * 32 + fm * 16 + l4 * 4;
        #pragma unroll
        for (int fn = 0; fn < 2; ++fn) {
            int jg = col0 + wn * 32 + fn * 16 + l15;
            #pragma unroll
            for (int e = 0; e < 4; ++e) {
                float vv = acc[fm][fn][e];
                int p = rbase + e;
                if (jg < O) outU[(size_t)p * O + jg] = vv;
                else        outV[(size_t)p * O + (jg - O)] = vv;
            }
        }
    }
}

// ---------------------------------------------------------------------------
// Single-plane bf16 MFMA GEMM, 128x128 tile (final conv only; output layer,
// so pure-bf16 error (~0.003 rel) is within budget).
__global__ __launch_bounds__(256) void mfma_gemm128s(const unsigned short* __restrict__ Xh,
                                                     int ldx, int K,
                                                     const unsigned short* __restrict__ Bh,
                                                     int O,
                                                     float* __restrict__ outU) {
    __shared__ unsigned short Ah[512 * 8], Bhs[512 * 8];
    int row0 = blockIdx.x * 128, col0 = blockIdx.y * 128;
    int tid = threadIdx.x;
    int wid = tid >> 6, lane = tid & 63;
    int wm = wid & 1, wn = wid >> 1;
    int l15 = lane & 15, l4 = lane >> 4;

    f4 acc[4][4];
    #pragma unroll
    for (int i = 0; i < 4; ++i)
        #pragma unroll
        for (int j = 0; j < 4; ++j) { acc[i][j][0]=0.f; acc[i][j][1]=0.f; acc[i][j][2]=0.f; acc[i][j][3]=0.f; }

    for (int k0 = 0; k0 < K; k0 += 32) {
        #pragma unroll
        for (int j = 0; j < 2; ++j) {
            int c = tid + 256 * j;
            int m = c & 127, kb = c >> 7;
            size_t ga = (size_t)(row0 + m) * ldx + k0 + kb * 8;
            size_t gb = (size_t)(col0 + m) * K + k0 + kb * 8;
            gload16(Xh + ga, &Ah[(size_t)(wid * 64 + 256 * j) * 8]);
            gload16(Bh + gb, &Bhs[(size_t)(wid * 64 + 256 * j) * 8]);
        }
        __syncthreads();

        sv8 bhf[4];
        #pragma unroll
        for (int fn = 0; fn < 4; ++fn) {
            int nn2 = wn * 64 + fn * 16 + l15;
            bhf[fn] = *(const sv8*)&Bhs[(size_t)(l4 * 128 + nn2) * 8];
        }
        #pragma unroll
        for (int fm = 0; fm < 4; ++fm) {
            int mm = wm * 64 + fm * 16 + l15;
            sv8 ah = *(const sv8*)&Ah[(size_t)(l4 * 128 + mm) * 8];
            #pragma unroll
            for (int fn = 0; fn < 4; ++fn)
                acc[fm][fn] = __builtin_amdgcn_mfma_f32_16x16x32_bf16(ah, bhf[fn], acc[fm][fn], 0, 0, 0);
        }
        __syncthreads();
    }

    #pragma unroll
    for (int fm = 0; fm < 4; ++fm) {
        int rbase = row0 + wm * 64 + fm * 16 + l4 * 4;
        #pragma unroll
        for (int fn = 0; fn < 4; ++fn) {
            int jg = col0 + wn * 64 + fn * 16 + l15;
            #pragma unroll
            for (int e = 0; e < 4; ++e)
                outU[(size_t)(rbase + e) * O + jg] = acc[fm][fn][e];
        }
    }
}

// ---------------------------------------------------------------------------
// edge_stats v2 (verified R6): float2 channel pairs, full prefetch, LDS reduce.
__global__ __launch_bounds__(256) void edge_stats(const float* __restrict__ u,
                                                  const float* __restrict__ v,
                                                  const int* __restrict__ idx,
                                                  int O, int PPL,
                                                  float* __restrict__ mx, float* __restrict__ mn,
                                                  float* __restrict__ partial) {
    __shared__ float red[4 * 256];
    int tid = threadIdx.x;
    int CH2 = O >> 1;
    int PS = 256 / CH2;
    int co = tid % CH2;
    int ps = tid / CH2;
    float s1a = 0.f, s1b = 0.f, s2a = 0.f, s2b = 0.f;
    for (int pi = 0; pi < PPL; ++pi) {
        int r = (blockIdx.x * PS + ps) * PPL + pi;
        int b = r >> 12;
        const float* ub = u + (size_t)b * NN * O + 2 * co;
        float2 vv = *(const float2*)&v[(size_t)r * O + 2 * co];
        const int* ip = idx + (size_t)r * KK;
        int mreg[KK];
        #pragma unroll
        for (int k = 0; k < KK; ++k) mreg[k] = ip[k];
        float2 uv[KK];
        #pragma unroll
        for (int k = 0; k < KK; ++k) uv[k] = *(const float2*)&ub[(size_t)mreg[k] * O];
        float bxa = -INFINITY, bxb = -INFINITY, bna = INFINITY, bnb = INFINITY;
        #pragma unroll
        for (int k = 0; k < KK; ++k) {
            float y0 = uv[k].x + vv.x, y1 = uv[k].y + vv.y;
            s1a += y0; s2a = fmaf(y0, y0, s2a);
            s1b += y1; s2b = fmaf(y1, y1, s2b);
            bxa = fmaxf(bxa, y0); bna = fminf(bna, y0);
            bxb = fmaxf(bxb, y1); bnb = fminf(bnb, y1);
        }
        *(float2*)&mx[(size_t)r * O + 2 * co] = make_float2(bxa, bxb);
        *(float2*)&mn[(size_t)r * O + 2 * co] = make_float2(bna, bnb);
    }
    red[0 * 256 + tid] = s1a;
    red[1 * 256 + tid] = s1b;
    red[2 * 256 + tid] = s2a;
    red[3 * 256 + tid] = s2b;
    __syncthreads();
    for (int s = PS >> 1; s > 0; s >>= 1) {
        if (ps < s) {
            int oth = tid + s * CH2;
            red[0 * 256 + tid] += red[0 * 256 + oth];
            red[1 * 256 + tid] += red[1 * 256 + oth];
            red[2 * 256 + tid] += red[2 * 256 + oth];
            red[3 * 256 + tid] += red[3 * 256 + oth];
        }
        __syncthreads();
    }
    if (ps == 0) {
        size_t base = (size_t)blockIdx.x * 2 * O;
        partial[base + 2 * co]         = red[0 * 256 + tid];
        partial[base + 2 * co + 1]     = red[1 * 256 + tid];
        partial[base + O + 2 * co]     = red[2 * 256 + tid];
        partial[base + O + 2 * co + 1] = red[3 * 256 + tid];
    }
}

// reduce partial[blk][2*O] -> per-channel scale/shift.  grid = O blocks.
__global__ __launch_bounds__(256) void stats_reduce(const float* __restrict__ partial, int nblk,
                                                    int O, float cnt,
                                                    const float* __restrict__ g,
                                                    const float* __restrict__ bsh,
                                                    float* __restrict__ st) {
    __shared__ float r1[4], r2[4];
    int o = blockIdx.x, tid = threadIdx.x;
    float s1 = 0.f, s2 = 0.f;
    for (int bk = tid; bk < nblk; bk += 256) {
        size_t base = (size_t)bk * 2 * O;
        s1 += partial[base + o];
        s2 += partial[base + O + o];
    }
    #pragma unroll
    for (int s = 32; s > 0; s >>= 1) {
        s1 += __shfl_down(s1, s, 64);
        s2 += __shfl_down(s2, s, 64);
    }
    if ((tid & 63) == 0) { r1[tid >> 6] = s1; r2[tid >> 6] = s2; }
    __syncthreads();
    if (tid == 0) {
        s1 = r1[0] + r1[1] + r1[2] + r1[3];
        s2 = r2[0] + r2[1] + r2[2] + r2[3];
        float mu = s1 / cnt;
        float var = s2 / cnt - mu * mu;
        float x = var + EPSB;
        float rr = rsqrtf(x);
        rr = rr * (1.5f - 0.5f * x * rr * rr);
        float sc = g[o] * rr;
        st[o] = sc;
        st[O + o] = bsh[o] - mu * sc;
    }
}

// select max/min by scale sign, affine + LeakyReLU; 2 channels/thread, packed
// 4B stores of bf16 pairs. writelo=0 skips the unused lo plane (layer 4).
__global__ void apply_edge(const float* __restrict__ mx, const float* __restrict__ mn,
                           const float* __restrict__ st, int O, int choff,
                           unsigned short* __restrict__ xh, unsigned short* __restrict__ xl,
                           int writelo) {
    int e2 = blockIdx.x * 256 + threadIdx.x;
    int half = O >> 1;
    if (e2 >= PP * half) return;
    int r = e2 / half, o = (e2 - r * half) * 2;
    float2 sc = *(const float2*)&st[o];
    float2 tt = *(const float2*)&st[O + o];
    float2 vx = *(const float2*)&mx[(size_t)r * O + o];
    float2 vn = *(const float2*)&mn[(size_t)r * O + o];
    float b0 = (sc.x >= 0.f) ? vx.x : vn.x;
    float b1 = (sc.y >= 0.f) ? vx.y : vn.y;
    float y0 = fmaf(sc.x, b0, tt.x); y0 = (y0 >= 0.f) ? y0 : LEAK * y0;
    float y1 = fmaf(sc.y, b1, tt.y); y1 = (y1 >= 0.f) ? y1 : LEAK * y1;
    unsigned short h0 = f2bf(y0), h1 = f2bf(y1);
    size_t d = (size_t)r * 512 + choff + o;
    ((unsigned int*)xh)[d >> 1] = (unsigned int)h0 | ((unsigned int)h1 << 16);
    if (writelo) {
        unsigned short l0 = f2bf(y0 - bf2f(h0)), l1 = f2bf(y1 - bf2f(h1));
        ((unsigned int*)xl)[d >> 1] = (unsigned int)l0 | ((unsigned int)l1 << 16);
    }
}

// ---------------------------------------------------------------------------
// Final BN stats over y5 (PP x 512)
__global__ __launch_bounds__(256) void final_stats(const float* __restrict__ y5,
                                                   float* __restrict__ partial) {
    int blk = blockIdx.x, t = threadIdx.x;
    float s1a = 0.f, s2a = 0.f, s1b = 0.f, s2b = 0.f;
    for (int rr = 0; rr < 128; ++rr) {
        size_t row = (size_t)(blk * 128 + rr) * 512;
        float va = y5[row + t], vb = y5[row + t + 256];
        s1a += va; s2a = fmaf(va, va, s2a);
        s1b += vb; s2b = fmaf(vb, vb, s2b);
    }
    partial[((size_t)blk * 512 + t) * 2 + 0] = s1a;
    partial[((size_t)blk * 512 + t) * 2 + 1] = s2a;
    partial[((size_t)blk * 512 + t + 256) * 2 + 0] = s1b;
    partial[((size_t)blk * 512 + t + 256) * 2 + 1] = s2b;
}

// grid = 512 blocks, 64 threads: one channel per block
__global__ __launch_bounds__(64) void final_reduce(const float* __restrict__ partial, int nblk,
                                                   float cnt,
                                                   const float* __restrict__ g,
                                                   const float* __restrict__ bsh,
                                                   float* __restrict__ st) {
    int c = blockIdx.x, tid = threadIdx.x;
    float s1 = 0.f, s2 = 0.f;
    for (int bk = tid; bk < nblk; bk += 64) {
        size_t base = ((size_t)bk * 512 + c) * 2;
        s1 += partial[base];
        s2 += partial[base + 1];
    }
    #pragma unroll
    for (int s = 32; s > 0; s >>= 1) {
        s1 += __shfl_down(s1, s, 64);
        s2 += __shfl_down(s2, s, 64);
    }
    if (tid == 0) {
        float mu = s1 / cnt;
        float var = s2 / cnt - mu * mu;
        float x = var + EPSB;
        float rr = rsqrtf(x);
        rr = rr * (1.5f - 0.5f * x * rr * rr);
        float sc = g[c] * rr;
        st[c] = sc;
        st[512 + c] = bsh[c] - mu * sc;
    }
}

// affine+lrelu + transpose (B,N,512) -> (B,512,N)
__global__ __launch_bounds__(256) void final_apply(const float* __restrict__ y5,
                                                   const float* __restrict__ st,
                                                   float* __restrict__ out) {
    __shared__ float tile[32][33];
    int n0 = blockIdx.x * 32, o0 = blockIdx.y * 32, b = blockIdx.z;
    int tx = threadIdx.x, ty = threadIdx.y;
    for (int i = 0; i < 4; ++i) {
        int nl = ty + i * 8;
        tile[nl][tx] = y5[((size_t)(b * NN + n0 + nl)) * 512 + o0 + tx];
    }
    __syncthreads();
    for (int i = 0; i < 4; ++i) {
        int ol = ty + i * 8;
        int o = o0 + ol;
        float sc = st[o], tt = st[512 + o];
        float yv = fmaf(sc, tile[tx][ol], tt);
        yv = (yv >= 0.f) ? yv : LEAK * yv;
        out[((size_t)b * 512 + o) * NN + n0 + tx] = yv;
    }
}

// ---------------------------------------------------------------------------
extern "C" void kernel_launch(void* const* d_in, const int* in_sizes, int n_in,
                              void* d_out, int out_size, void* d_ws, size_t ws_size,
                              hipStream_t stream) {
    const float* pts = (const float*)d_in[0];
    const float* w[5]; const float* g[5]; const float* bsh[5];
    for (int i = 0; i < 5; ++i) {
        w[i]   = (const float*)d_in[1 + 3 * i];
        g[i]   = (const float*)d_in[2 + 3 * i];
        bsh[i] = (const float*)d_in[3 + 3 * i];
    }
    float* out = (float*)d_out;

    // workspace layout
    unsigned short* xh = (unsigned short*)d_ws;              // PP*512 bf16 hi
    unsigned short* xl = xh + (size_t)PP * 512;              // PP*512 bf16 lo
    float* u    = (float*)(xl + (size_t)PP * 512);           // PP*256
    float* v    = u    + (size_t)PP * 256;                   // PP*256
    float* mxb  = v    + (size_t)PP * 256;                   // PP*256
    float* mnb  = mxb  + (size_t)PP * 256;                   // PP*256
    float* y5   = u;                                         // overlay u+v (PP*512)
    float* ptst = mnb  + (size_t)PP * 256;                   // PP*2
    int*   idxb = (int*)(ptst + (size_t)PP * 2);             // PP*20
    float* part = (float*)(idxb + (size_t)PP * KK);          // 1M floats (4MB)
    float* st   = part + (size_t)1048576;                    // 1024
    unsigned short* wh_all = (unsigned short*)(st + 1024);   // 352256 persistent
    unsigned short* wl_all = wh_all + 352256;                // 352256

    knn_kernel<<<PP, 256, 0, stream>>>(pts, idxb, ptst);
    convert_all<<<1376, 256, 0, stream>>>(w[1], w[2], w[3], w[4], wh_all, wl_all);

    const int Cs[4]    = {2, 64, 64, 128};
    const int Os[4]    = {64, 64, 128, 256};
    const int choffs[4]= {0, 64, 128, 256};
    const int inoffs[4]= {0, 0, 64, 128};
    const int woffs[4] = {0, 0, 8192, 24576};

    for (int li = 0; li < 4; ++li) {
        int C = Cs[li], O = Os[li];
        if (li == 0) {
            dim3 gg(PP / 64, (2 * O) / 64);
            proj_gemm<<<gg, 256, 0, stream>>>(ptst, 2, C, w[0], O, 0, u, v);
        } else {
            dim3 gg(PP / 64, (2 * O) / 64);
            mfma_gemm64<<<gg, 256, 0, stream>>>(xh + inoffs[li], xl + inoffs[li], 512, C,
                                                wh_all + woffs[li], wl_all + woffs[li], O, u, v);
        }
        int PS  = 512 / O;
        int PPL = (O == 256) ? 2 : 1;
        int nblk = PP / (PS * PPL);
        edge_stats<<<nblk, 256, 0, stream>>>(u, v, idxb, O, PPL, mxb, mnb, part);
        stats_reduce<<<O, 256, 0, stream>>>(part, nblk, O, (float)((size_t)PP * KK),
                                            g[li], bsh[li], st);
        apply_edge<<<(PP * O / 2 + 255) / 256, 256, 0, stream>>>(
            mxb, mnb, st, O, choffs[li], xh, xl, (li == 3) ? 0 : 1);
    }

    // final conv1d 512->512 (single-plane bf16 MFMA) + BN + lrelu, transposed
    dim3 gf(PP / 128, 512 / 128);
    mfma_gemm128s<<<gf, 256, 0, stream>>>(xh, 512, 512, wh_all + 90112, 512, y5);
    final_stats<<<64, 256, 0, stream>>>(y5, part);
    final_reduce<<<512, 64, 0, stream>>>(part, 64, (float)PP, g[4], bsh[4], st);
    final_apply<<<dim3(NN / 32, 512 / 32, BB), dim3(32, 8), 0, stream>>>(y5, st, out);
}

// Round 8
// 186.604 us; speedup vs baseline: 6.0729x; 1.0397x over previous
//
#include <hip/hip_runtime.h>
#include <hip/hip_bf16.h>
#include <math.h>

// Problem constants
#define BB 2
#define NN 4096
#define PP (BB*NN)      // 8192 points total
#define KK 20
#define LEAK 0.2f
#define EPSB 1e-5f

typedef short sv8 __attribute__((ext_vector_type(8)));   // 8 bf16 (4 VGPRs)
typedef float f4  __attribute__((ext_vector_type(4)));   // 4 fp32 acc

__device__ inline unsigned short f2bf(float f) {         // RNE fp32->bf16
    unsigned u = __float_as_uint(f);
    unsigned r = (u + 0x7FFFu + ((u >> 16) & 1u)) >> 16;
    return (unsigned short)r;
}
__device__ inline float bf2f(unsigned short h) {
    return __uint_as_float((unsigned)h << 16);
}
__device__ inline void gload16(const void* g, void* l) {
    __builtin_amdgcn_global_load_lds(
        (const __attribute__((address_space(1))) unsigned int*)g,
        (__attribute__((address_space(3))) unsigned int*)l, 16, 0, 0);
}

// ---------------------------------------------------------------------------
// kNN v5: histogram radix-select with register-cached bins (no key recompute
// in the classify pass). Distance arithmetic identical to verified R1-R7.
__global__ __launch_bounds__(256) void knn_kernel(const float* __restrict__ pts,
                                                  int* __restrict__ idx) {
    __shared__ unsigned int hist[256];
    __shared__ unsigned int scanres[3];
    __shared__ unsigned int cnt2[2];
    __shared__ unsigned long long blist[512];

    int r = blockIdx.x;            // b*N + n
    int b = r >> 12, n = r & (NN - 1);
    const float* X0 = pts + (size_t)b * 2 * NN;
    const float* X1 = X0 + NN;
    int tid = threadIdx.x;
    float x0n = X0[n], x1n = X1[n];
    float xxn = __fadd_rn(__fmul_rn(x0n, x0n), __fmul_rn(x1n, x1n));
    float negxxn = __fsub_rn(0.f, xxn);

    float pdv[16];
    #pragma unroll
    for (int q = 0; q < 16; ++q) {
        int m = q * 256 + tid;
        float x0m = X0[m], x1m = X1[m];
        float xxm = __fadd_rn(__fmul_rn(x0m, x0m), __fmul_rn(x1m, x1m));
        float dot = __builtin_fmaf(x1n, x1m, __fmul_rn(x0n, x0m));
        float inner = __fmul_rn(-2.f, dot);
        float t1 = __fsub_rn(negxxn, inner);
        pdv[q] = __fsub_rn(t1, xxm);
    }

    int bins[16];
    int shift = 24;
    for (int attempt = 0; attempt < 3; ++attempt) {
        hist[tid] = 0;
        __syncthreads();
        float scale = (float)(1u << shift);
        #pragma unroll
        for (int q = 0; q < 16; ++q) {
            float s = fmaxf(-pdv[q], 0.f);
            unsigned int ki = (unsigned int)fminf(s * scale, 4.294e9f);
            unsigned int bin = ki >> 16;
            if (bin > 255u) bin = 255u;
            bins[q] = (int)bin;
            if (bin < 255u) atomicAdd(&hist[bin], 1u);
        }
        __syncthreads();
        if (tid < 64) {
            uint4 hv = *(const uint4*)&hist[tid * 4];
            unsigned int p0 = hv.x, p1 = p0 + hv.y, p2 = p1 + hv.z, p3 = p2 + hv.w;
            unsigned int lanesum = p3, inc = p3;
            #pragma unroll
            for (int s2 = 1; s2 < 64; s2 <<= 1) {
                unsigned int o = __shfl_up(inc, s2, 64);
                if (tid >= s2) inc += o;
            }
            unsigned int excl = inc - lanesum;
            bool flag = (inc >= KK);
            unsigned long long bal = __ballot(flag);
            int firstlane = (bal == 0ULL) ? -1 : (__ffsll((long long)bal) - 1);
            if (tid == 0) scanres[0] = (bal != 0ULL) ? 1u : 0u;
            if (tid == firstlane) {
                unsigned int c0 = excl + p0, c1 = excl + p1, c2 = excl + p2;
                int t = (c0 >= KK) ? 0 : (c1 >= KK) ? 1 : (c2 >= KK) ? 2 : 3;
                unsigned int cumb = (t == 0) ? excl : (t == 1) ? c0 : (t == 2) ? c1 : c2;
                scanres[1] = (unsigned)(tid * 4 + t);
                scanres[2] = cumb;
            }
        }
        __syncthreads();
        if (scanres[0]) break;
        shift -= 6;
        __syncthreads();
    }

    int bstar = (int)scanres[1];
    unsigned int cumb = scanres[2];
    if (tid == 0) { cnt2[0] = 0; cnt2[1] = 0; }
    __syncthreads();

    #pragma unroll
    for (int q = 0; q < 16; ++q) {
        int bin = bins[q];
        int m = q * 256 + tid;
        if (bin < bstar) {
            unsigned int slot = atomicAdd(&cnt2[0], 1u);
            idx[(size_t)r * KK + slot] = m;
        } else if (bin == bstar) {
            unsigned int pos = atomicAdd(&cnt2[1], 1u);
            if (pos < 512u) {
                unsigned int ub = __float_as_uint(pdv[q]);
                unsigned int fk = (ub & 0x80000000u) ? ~ub : (ub | 0x80000000u);
                blist[pos] = ((unsigned long long)(~fk) << 32) | (unsigned int)m;
            }
        }
    }
    __syncthreads();

    int need = KK - (int)cumb;
    int L = (int)min(cnt2[1], 512u);
    if (tid < 64) {
        unsigned long long e[8];
        #pragma unroll
        for (int i = 0; i < 8; ++i) {
            int p = tid + 64 * i;
            e[i] = (p < L) ? blist[p] : ~0ULL;
        }
        unsigned long long lmin = e[0];
        #pragma unroll
        for (int i = 1; i < 8; ++i) lmin = (e[i] < lmin) ? e[i] : lmin;
        for (int p = 0; p < need; ++p) {
            unsigned long long gm = lmin;
            #pragma unroll
            for (int s2 = 32; s2 > 0; s2 >>= 1) {
                unsigned long long o = __shfl_xor(gm, s2, 64);
                if (o < gm) gm = o;
            }
            if (lmin == gm) {
                #pragma unroll
                for (int i = 0; i < 8; ++i) if (e[i] == gm) e[i] = ~0ULL;
                lmin = e[0];
                #pragma unroll
                for (int i = 1; i < 8; ++i) lmin = (e[i] < lmin) ? e[i] : lmin;
                idx[(size_t)r * KK + cumb + p] = (int)(gm & 0xFFFFFFFFu);
            }
        }
    }
}

// ---------------------------------------------------------------------------
// Layer-1 projection (K=2): u[r][o] = wA·x_r, v[r][o] = (wB-wA)·x_r.
// w1 row o: [wA0, wA1, wB0, wB1].
__global__ __launch_bounds__(256) void l1_proj(const float* __restrict__ pts,
                                               const float* __restrict__ w1,
                                               float* __restrict__ u,
                                               float* __restrict__ v) {
    int e = blockIdx.x * 256 + threadIdx.x;   // PP*64
    int r = e >> 6, o = e & 63;
    int b = r >> 12, n = r & (NN - 1);
    float x0 = pts[(size_t)b * 2 * NN + n];
    float x1 = pts[(size_t)b * 2 * NN + NN + n];
    float4 wr = *(const float4*)&w1[(size_t)o * 4];
    u[(size_t)r * 64 + o] = fmaf(wr.x, x0, wr.y * x1);
    v[(size_t)r * 64 + o] = fmaf(wr.z - wr.x, x0, (wr.w - wr.y) * x1);
}

// ---------------------------------------------------------------------------
// One-shot weight conversion for layers 2..5 into persistent hi/lo planes.
__global__ __launch_bounds__(256) void convert_all(const float* __restrict__ w2,
                                                   const float* __restrict__ w3,
                                                   const float* __restrict__ w4,
                                                   const float* __restrict__ w5,
                                                   unsigned short* __restrict__ bh,
                                                   unsigned short* __restrict__ bl) {
    int i = blockIdx.x * 256 + threadIdx.x;
    if (i >= 352256) return;
    const float* w; int O, C, mode, base;
    if (i < 8192)       { w = w2; O = 64;  C = 64;  mode = 0; base = 0; }
    else if (i < 24576) { w = w3; O = 128; C = 64;  mode = 0; base = 8192; }
    else if (i < 90112) { w = w4; O = 256; C = 128; mode = 0; base = 24576; }
    else                { w = w5; O = 512; C = 512; mode = 1; base = 90112; }
    int j = i - base;
    int row = j / C, c = j - row * C;
    float v;
    if (mode == 0) {
        if (row < O) v = w[(size_t)row * 2 * C + c];
        else {
            const float* wr = w + (size_t)(row - O) * 2 * C;
            v = wr[C + c] - wr[c];
        }
    } else {
        v = w[(size_t)row * C + c];
    }
    unsigned short h = f2bf(v);
    bh[i] = h;
    bl[i] = f2bf(v - bf2f(h));
}

// ---------------------------------------------------------------------------
// Split-bf16 MFMA GEMM, 64x64 tile (verified R7).
__global__ __launch_bounds__(256) void mfma_gemm64(const unsigned short* __restrict__ Xh,
                                                   const unsigned short* __restrict__ Xl,
                                                   int ldx, int K,
                                                   const unsigned short* __restrict__ Bh,
                                                   const unsigned short* __restrict__ Bl,
                                                   int O,
                                                   float* __restrict__ outU,
                                                   float* __restrict__ outV) {
    __shared__ unsigned short Ah[256 * 8], Al[256 * 8], Bhs[256 * 8], Bls[256 * 8];
    int row0 = blockIdx.x * 64, col0 = blockIdx.y * 64;
    int tid = threadIdx.x;
    int wid = tid >> 6, lane = tid & 63;
    int wm = wid & 1, wn = wid >> 1;
    int l15 = lane & 15, l4 = lane >> 4;
    int m = tid & 63, kb = tid >> 6;

    f4 acc[2][2];
    #pragma unroll
    for (int i = 0; i < 2; ++i)
        #pragma unroll
        for (int j = 0; j < 2; ++j) { acc[i][j][0]=0.f; acc[i][j][1]=0.f; acc[i][j][2]=0.f; acc[i][j][3]=0.f; }

    for (int k0 = 0; k0 < K; k0 += 32) {
        size_t ga = (size_t)(row0 + m) * ldx + k0 + kb * 8;
        size_t gb = (size_t)(col0 + m) * K + k0 + kb * 8;
        gload16(Xh + ga, &Ah[(size_t)(wid * 64) * 8]);
        gload16(Xl + ga, &Al[(size_t)(wid * 64) * 8]);
        gload16(Bh + gb, &Bhs[(size_t)(wid * 64) * 8]);
        gload16(Bl + gb, &Bls[(size_t)(wid * 64) * 8]);
        __syncthreads();

        sv8 bhf[2], blf[2];
        #pragma unroll
        for (int fn = 0; fn < 2; ++fn) {
            int nn2 = wn * 32 + fn * 16 + l15;
            bhf[fn] = *(const sv8*)&Bhs[(size_t)(l4 * 64 + nn2) * 8];
            blf[fn] = *(const sv8*)&Bls[(size_t)(l4 * 64 + nn2) * 8];
        }
        #pragma unroll
        for (int fm = 0; fm < 2; ++fm) {
            int mm = wm * 32 + fm * 16 + l15;
            sv8 ah = *(const sv8*)&Ah[(size_t)(l4 * 64 + mm) * 8];
            sv8 al = *(const sv8*)&Al[(size_t)(l4 * 64 + mm) * 8];
            #pragma unroll
            for (int fn = 0; fn < 2; ++fn) {
                acc[fm][fn] = __builtin_amdgcn_mfma_f32_16x16x32_bf16(ah, bhf[fn], acc[fm][fn], 0, 0, 0);
                acc[fm][fn] = __builtin_amdgcn_mfma_f32_16x16x32_bf16(ah, blf[fn], acc[fm][fn], 0, 0, 0);
                acc[fm][fn] = __builtin_amdgcn_mfma_f32_16x16x32_bf16(al, bhf[fn], acc[fm][fn], 0, 0, 0);
            }
        }
        __syncthreads();
    }

    #pragma unroll
    for (int fm = 0; fm < 2; ++fm) {
        int rbase = row0 + wm * 32 + fm * 16 + l4 * 4;
        #pragma unroll
        for (int fn = 0; fn < 2; ++fn) {
            int jg = col0 + wn * 32 + fn * 16 + l15;
            #pragma unroll
            for (int e = 0; e < 4; ++e) {
                float vv = acc[fm][fn][e];
                int p = rbase + e;
                if (jg < O) outU[(size_t)p * O + jg] = vv;
                else        outV[(size_t)p * O + (jg - O)] = vv;
            }
        }
    }
}

// ---------------------------------------------------------------------------
// Single-plane bf16 MFMA GEMM, 128x128 tile (final conv) + fused per-channel
// partial BN stats: partial[rowblk*1024 + col*2 + {0,1}] = (sum y, sum y^2)
// over the block's 128 rows.
__global__ __launch_bounds__(256) void mfma_gemm128s(const unsigned short* __restrict__ Xh,
                                                     int ldx, int K,
                                                     const unsigned short* __restrict__ Bh,
                                                     int O,
                                                     float* __restrict__ outU,
                                                     float* __restrict__ partial) {
    __shared__ unsigned short Ah[512 * 8], Bhs[512 * 8];
    __shared__ float sred1[2][128], sred2[2][128];
    int row0 = blockIdx.x * 128, col0 = blockIdx.y * 128;
    int tid = threadIdx.x;
    int wid = tid >> 6, lane = tid & 63;
    int wm = wid & 1, wn = wid >> 1;
    int l15 = lane & 15, l4 = lane >> 4;

    f4 acc[4][4];
    #pragma unroll
    for (int i = 0; i < 4; ++i)
        #pragma unroll
        for (int j = 0; j < 4; ++j) { acc[i][j][0]=0.f; acc[i][j][1]=0.f; acc[i][j][2]=0.f; acc[i][j][3]=0.f; }

    for (int k0 = 0; k0 < K; k0 += 32) {
        #pragma unroll
        for (int j = 0; j < 2; ++j) {
            int c = tid + 256 * j;
            int m = c & 127, kb = c >> 7;
            size_t ga = (size_t)(row0 + m) * ldx + k0 + kb * 8;
            size_t gb = (size_t)(col0 + m) * K + k0 + kb * 8;
            gload16(Xh + ga, &Ah[(size_t)(wid * 64 + 256 * j) * 8]);
            gload16(Bh + gb, &Bhs[(size_t)(wid * 64 + 256 * j) * 8]);
        }
        __syncthreads();

        sv8 bhf[4];
        #pragma unroll
        for (int fn = 0; fn < 4; ++fn) {
            int nn2 = wn * 64 + fn * 16 + l15;
            bhf[fn] = *(const sv8*)&Bhs[(size_t)(l4 * 128 + nn2) * 8];
        }
        #pragma unroll
        for (int fm = 0; fm < 4; ++fm) {
            int mm = wm * 64 + fm * 16 + l15;
            sv8 ah = *(const sv8*)&Ah[(size_t)(l4 * 128 + mm) * 8];
            #pragma unroll
            for (int fn = 0; fn < 4; ++fn)
                acc[fm][fn] = __builtin_amdgcn_mfma_f32_16x16x32_bf16(ah, bhf[fn], acc[fm][fn], 0, 0, 0);
        }
        __syncthreads();
    }

    // C write
    #pragma unroll
    for (int fm = 0; fm < 4; ++fm) {
        int rbase = row0 + wm * 64 + fm * 16 + l4 * 4;
        #pragma unroll
        for (int fn = 0; fn < 4; ++fn) {
            int jg = col0 + wn * 64 + fn * 16 + l15;
            #pragma unroll
            for (int e = 0; e < 4; ++e)
                outU[(size_t)(rbase + e) * O + jg] = acc[fm][fn][e];
        }
    }

    // fused per-channel partial stats over this block's 128 rows
    #pragma unroll
    for (int fn = 0; fn < 4; ++fn) {
        float a1 = 0.f, a2 = 0.f;
        #pragma unroll
        for (int fm = 0; fm < 4; ++fm)
            #pragma unroll
            for (int e = 0; e < 4; ++e) { float t = acc[fm][fn][e]; a1 += t; a2 = fmaf(t, t, a2); }
        a1 += __shfl_xor(a1, 16, 64); a2 += __shfl_xor(a2, 16, 64);
        a1 += __shfl_xor(a1, 32, 64); a2 += __shfl_xor(a2, 32, 64);
        if (lane < 16) {
            int cb = wn * 64 + fn * 16 + lane;
            sred1[wm][cb] = a1;
            sred2[wm][cb] = a2;
        }
    }
    __syncthreads();
    if (tid < 128) {
        float s1 = sred1[0][tid] + sred1[1][tid];
        float s2 = sred2[0][tid] + sred2[1][tid];
        size_t pbase = (size_t)blockIdx.x * 1024 + (size_t)(col0 + tid) * 2;
        partial[pbase]     = s1;
        partial[pbase + 1] = s2;
    }
}

// ---------------------------------------------------------------------------
// edge_stats v2 (verified R6/R7).
__global__ __launch_bounds__(256) void edge_stats(const float* __restrict__ u,
                                                  const float* __restrict__ v,
                                                  const int* __restrict__ idx,
                                                  int O, int PPL,
                                                  float* __restrict__ mx, float* __restrict__ mn,
                                                  float* __restrict__ partial) {
    __shared__ float red[4 * 256];
    int tid = threadIdx.x;
    int CH2 = O >> 1;
    int PS = 256 / CH2;
    int co = tid % CH2;
    int ps = tid / CH2;
    float s1a = 0.f, s1b = 0.f, s2a = 0.f, s2b = 0.f;
    for (int pi = 0; pi < PPL; ++pi) {
        int r = (blockIdx.x * PS + ps) * PPL + pi;
        int b = r >> 12;
        const float* ub = u + (size_t)b * NN * O + 2 * co;
        float2 vv = *(const float2*)&v[(size_t)r * O + 2 * co];
        const int* ip = idx + (size_t)r * KK;
        int mreg[KK];
        #pragma unroll
        for (int k = 0; k < KK; ++k) mreg[k] = ip[k];
        float2 uv[KK];
        #pragma unroll
        for (int k = 0; k < KK; ++k) uv[k] = *(const float2*)&ub[(size_t)mreg[k] * O];
        float bxa = -INFINITY, bxb = -INFINITY, bna = INFINITY, bnb = INFINITY;
        #pragma unroll
        for (int k = 0; k < KK; ++k) {
            float y0 = uv[k].x + vv.x, y1 = uv[k].y + vv.y;
            s1a += y0; s2a = fmaf(y0, y0, s2a);
            s1b += y1; s2b = fmaf(y1, y1, s2b);
            bxa = fmaxf(bxa, y0); bna = fminf(bna, y0);
            bxb = fmaxf(bxb, y1); bnb = fminf(bnb, y1);
        }
        *(float2*)&mx[(size_t)r * O + 2 * co] = make_float2(bxa, bxb);
        *(float2*)&mn[(size_t)r * O + 2 * co] = make_float2(bna, bnb);
    }
    red[0 * 256 + tid] = s1a;
    red[1 * 256 + tid] = s1b;
    red[2 * 256 + tid] = s2a;
    red[3 * 256 + tid] = s2b;
    __syncthreads();
    for (int s = PS >> 1; s > 0; s >>= 1) {
        if (ps < s) {
            int oth = tid + s * CH2;
            red[0 * 256 + tid] += red[0 * 256 + oth];
            red[1 * 256 + tid] += red[1 * 256 + oth];
            red[2 * 256 + tid] += red[2 * 256 + oth];
            red[3 * 256 + tid] += red[3 * 256 + oth];
        }
        __syncthreads();
    }
    if (ps == 0) {
        size_t base = (size_t)blockIdx.x * 2 * O;
        partial[base + 2 * co]         = red[0 * 256 + tid];
        partial[base + 2 * co + 1]     = red[1 * 256 + tid];
        partial[base + O + 2 * co]     = red[2 * 256 + tid];
        partial[base + O + 2 * co + 1] = red[3 * 256 + tid];
    }
}

// reduce partial[blk][2*O] -> per-channel scale/shift.  grid = O blocks.
__global__ __launch_bounds__(256) void stats_reduce(const float* __restrict__ partial, int nblk,
                                                    int O, float cnt,
                                                    const float* __restrict__ g,
                                                    const float* __restrict__ bsh,
                                                    float* __restrict__ st) {
    __shared__ float r1[4], r2[4];
    int o = blockIdx.x, tid = threadIdx.x;
    float s1 = 0.f, s2 = 0.f;
    for (int bk = tid; bk < nblk; bk += 256) {
        size_t base = (size_t)bk * 2 * O;
        s1 += partial[base + o];
        s2 += partial[base + O + o];
    }
    #pragma unroll
    for (int s = 32; s > 0; s >>= 1) {
        s1 += __shfl_down(s1, s, 64);
        s2 += __shfl_down(s2, s, 64);
    }
    if ((tid & 63) == 0) { r1[tid >> 6] = s1; r2[tid >> 6] = s2; }
    __syncthreads();
    if (tid == 0) {
        s1 = r1[0] + r1[1] + r1[2] + r1[3];
        s2 = r2[0] + r2[1] + r2[2] + r2[3];
        float mu = s1 / cnt;
        float var = s2 / cnt - mu * mu;
        float x = var + EPSB;
        float rr = rsqrtf(x);
        rr = rr * (1.5f - 0.5f * x * rr * rr);
        float sc = g[o] * rr;
        st[o] = sc;
        st[O + o] = bsh[o] - mu * sc;
    }
}

// select max/min by scale sign, affine + LeakyReLU; 2 channels/thread.
__global__ void apply_edge(const float* __restrict__ mx, const float* __restrict__ mn,
                           const float* __restrict__ st, int O, int choff,
                           unsigned short* __restrict__ xh, unsigned short* __restrict__ xl,
                           int writelo) {
    int e2 = blockIdx.x * 256 + threadIdx.x;
    int half = O >> 1;
    if (e2 >= PP * half) return;
    int r = e2 / half, o = (e2 - r * half) * 2;
    float2 sc = *(const float2*)&st[o];
    float2 tt = *(const float2*)&st[O + o];
    float2 vx = *(const float2*)&mx[(size_t)r * O + o];
    float2 vn = *(const float2*)&mn[(size_t)r * O + o];
    float b0 = (sc.x >= 0.f) ? vx.x : vn.x;
    float b1 = (sc.y >= 0.f) ? vx.y : vn.y;
    float y0 = fmaf(sc.x, b0, tt.x); y0 = (y0 >= 0.f) ? y0 : LEAK * y0;
    float y1 = fmaf(sc.y, b1, tt.y); y1 = (y1 >= 0.f) ? y1 : LEAK * y1;
    unsigned short h0 = f2bf(y0), h1 = f2bf(y1);
    size_t d = (size_t)r * 512 + choff + o;
    ((unsigned int*)xh)[d >> 1] = (unsigned int)h0 | ((unsigned int)h1 << 16);
    if (writelo) {
        unsigned short l0 = f2bf(y0 - bf2f(h0)), l1 = f2bf(y1 - bf2f(h1));
        ((unsigned int*)xl)[d >> 1] = (unsigned int)l0 | ((unsigned int)l1 << 16);
    }
}

// ---------------------------------------------------------------------------
// final reduce over 64 rowblock partials: grid = 512 blocks, 64 threads.
__global__ __launch_bounds__(64) void final_reduce(const float* __restrict__ partial,
                                                   float cnt,
                                                   const float* __restrict__ g,
                                                   const float* __restrict__ bsh,
                                                   float* __restrict__ st) {
    int c = blockIdx.x, tid = threadIdx.x;
    size_t base = (size_t)tid * 1024 + (size_t)c * 2;
    float s1 = partial[base], s2 = partial[base + 1];
    #pragma unroll
    for (int s = 32; s > 0; s >>= 1) {
        s1 += __shfl_down(s1, s, 64);
        s2 += __shfl_down(s2, s, 64);
    }
    if (tid == 0) {
        float mu = s1 / cnt;
        float var = s2 / cnt - mu * mu;
        float x = var + EPSB;
        float rr = rsqrtf(x);
        rr = rr * (1.5f - 0.5f * x * rr * rr);
        float sc = g[c] * rr;
        st[c] = sc;
        st[512 + c] = bsh[c] - mu * sc;
    }
}

// affine+lrelu + transpose (B,N,512) -> (B,512,N)
__global__ __launch_bounds__(256) void final_apply(const float* __restrict__ y5,
                                                   const float* __restrict__ st,
                                                   float* __restrict__ out) {
    __shared__ float tile[32][33];
    int n0 = blockIdx.x * 32, o0 = blockIdx.y * 32, b = blockIdx.z;
    int tx = threadIdx.x, ty = threadIdx.y;
    for (int i = 0; i < 4; ++i) {
        int nl = ty + i * 8;
        tile[nl][tx] = y5[((size_t)(b * NN + n0 + nl)) * 512 + o0 + tx];
    }
    __syncthreads();
    for (int i = 0; i < 4; ++i) {
        int ol = ty + i * 8;
        int o = o0 + ol;
        float sc = st[o], tt = st[512 + o];
        float yv = fmaf(sc, tile[tx][ol], tt);
        yv = (yv >= 0.f) ? yv : LEAK * yv;
        out[((size_t)b * 512 + o) * NN + n0 + tx] = yv;
    }
}

// ---------------------------------------------------------------------------
extern "C" void kernel_launch(void* const* d_in, const int* in_sizes, int n_in,
                              void* d_out, int out_size, void* d_ws, size_t ws_size,
                              hipStream_t stream) {
    const float* pts = (const float*)d_in[0];
    const float* w[5]; const float* g[5]; const float* bsh[5];
    for (int i = 0; i < 5; ++i) {
        w[i]   = (const float*)d_in[1 + 3 * i];
        g[i]   = (const float*)d_in[2 + 3 * i];
        bsh[i] = (const float*)d_in[3 + 3 * i];
    }
    float* out = (float*)d_out;

    // workspace layout
    unsigned short* xh = (unsigned short*)d_ws;              // PP*512 bf16 hi
    unsigned short* xl = xh + (size_t)PP * 512;              // PP*512 bf16 lo
    float* u    = (float*)(xl + (size_t)PP * 512);           // PP*256
    float* v    = u    + (size_t)PP * 256;                   // PP*256
    float* mxb  = v    + (size_t)PP * 256;                   // PP*256
    float* mnb  = mxb  + (size_t)PP * 256;                   // PP*256
    float* y5   = u;                                         // overlay u+v (PP*512)
    float* ptst = mnb  + (size_t)PP * 256;                   // PP*2 (unused slot)
    int*   idxb = (int*)(ptst + (size_t)PP * 2);             // PP*20
    float* part = (float*)(idxb + (size_t)PP * KK);          // 1M floats (4MB)
    float* st   = part + (size_t)1048576;                    // 1024
    unsigned short* wh_all = (unsigned short*)(st + 1024);   // 352256 persistent
    unsigned short* wl_all = wh_all + 352256;                // 352256

    knn_kernel<<<PP, 256, 0, stream>>>(pts, idxb);
    convert_all<<<1376, 256, 0, stream>>>(w[1], w[2], w[3], w[4], wh_all, wl_all);

    const int Cs[4]    = {2, 64, 64, 128};
    const int Os[4]    = {64, 64, 128, 256};
    const int choffs[4]= {0, 64, 128, 256};
    const int inoffs[4]= {0, 0, 64, 128};
    const int woffs[4] = {0, 0, 8192, 24576};

    for (int li = 0; li < 4; ++li) {
        int C = Cs[li], O = Os[li];
        if (li == 0) {
            l1_proj<<<PP * 64 / 256, 256, 0, stream>>>(pts, w[0], u, v);
        } else {
            dim3 gg(PP / 64, (2 * O) / 64);
            mfma_gemm64<<<gg, 256, 0, stream>>>(xh + inoffs[li], xl + inoffs[li], 512, C,
                                                wh_all + woffs[li], wl_all + woffs[li], O, u, v);
        }
        int PS  = 512 / O;
        int PPL = (O == 256) ? 2 : 1;
        int nblk = PP / (PS * PPL);
        edge_stats<<<nblk, 256, 0, stream>>>(u, v, idxb, O, PPL, mxb, mnb, part);
        stats_reduce<<<O, 256, 0, stream>>>(part, nblk, O, (float)((size_t)PP * KK),
                                            g[li], bsh[li], st);
        apply_edge<<<(PP * O / 2 + 255) / 256, 256, 0, stream>>>(
            mxb, mnb, st, O, choffs[li], xh, xl, (li == 3) ? 0 : 1);
    }

    // final conv1d 512->512 (single-plane bf16 MFMA, fused BN partials)
    dim3 gf(PP / 128, 512 / 128);
    mfma_gemm128s<<<gf, 256, 0, stream>>>(xh, 512, 512, wh_all + 90112, 512, y5, part);
    final_reduce<<<512, 64, 0, stream>>>(part, (float)PP, g[4], bsh[4], st);
    final_apply<<<dim3(NN / 32, 512 / 32, BB), dim3(32, 8), 0, stream>>>(y5, st, out);
}